// Round 1
// baseline (408.682 us; speedup 1.0000x reference)
//
#include <hip/hip_runtime.h>
#include <math.h>

#define NT 13
#define RHW 57600  // 240*240

struct Meta {
  const float* x[NT];
  int C[NT];
  int H[NT];
  int W[NT];
  int chanOff[NT + 1];
  int pixOff[NT + 1];
  int blkOff[NT + 1];
};

__device__ __forceinline__ int findSeg(const int* off, int b) {
  int t = 0;
  while (t + 1 < NT && b >= off[t + 1]) t++;
  return t;
}

// ---------------- K1: per-channel masked min/max ----------------
__global__ __launch_bounds__(256) void k_chan_minmax(Meta m, float* cstats) {
  int b = blockIdx.x;
  int t = findSeg(m.chanOff, b);
  int c = b - m.chanOff[t];
  int H = m.H[t], W = m.W[t], HW = H * W;
  const float* p = m.x[t] + (size_t)c * HW;
  float mn = INFINITY, mx = -INFINITY;
  for (int i = threadIdx.x; i < HW; i += 256) {
    int h = i / W, w = i - h * W;
    float v = p[i];
    if (h == 0 || h == H - 1 || w == 0 || w == W - 1) v = 0.f;
    mn = fminf(mn, v); mx = fmaxf(mx, v);
  }
#pragma unroll
  for (int o = 32; o > 0; o >>= 1) {
    mn = fminf(mn, __shfl_down(mn, o));
    mx = fmaxf(mx, __shfl_down(mx, o));
  }
  __shared__ float smn[4], smx[4];
  int wid = threadIdx.x >> 6;
  if ((threadIdx.x & 63) == 0) { smn[wid] = mn; smx[wid] = mx; }
  __syncthreads();
  if (threadIdx.x == 0) {
    for (int i = 1; i < 4; i++) { mn = fminf(mn, smn[i]); mx = fmaxf(mx, smx[i]); }
    cstats[2 * b] = mn; cstats[2 * b + 1] = mx;
  }
}

// ---------------- K2: per-channel dual 6-bin histograms ----------------
__global__ __launch_bounds__(256) void k_hist(Meta m, const float* cstats, unsigned* hist) {
  int b = blockIdx.x;
  int t = findSeg(m.chanOff, b);
  int c = b - m.chanOff[t];
  int H = m.H[t], W = m.W[t], HW = H * W;
  const float* p = m.x[t] + (size_t)c * HW;
  float mn = cstats[2 * b], mx = cstats[2 * b + 1];
  float d = mx - mn;
  float invd = d > 0.f ? 1.0f / d : 0.f;
  __shared__ unsigned sh[12];
  if (threadIdx.x < 12) sh[threadIdx.x] = 0;
  __syncthreads();
  int lane = threadIdx.x & 63;
  unsigned cnt = 0;
  for (int i = threadIdx.x; i < HW; i += 256) {
    int h = i / W, w = i - h * W;
    float xv = p[i];
    if (h == 0 || h == H - 1 || w == 0 || w == W - 1) xv = 0.f;
    float v = (xv - mn) * invd * 256.0f;
    int bin = (int)(v * 0.0234375f);            // * (6/256)
    bin = bin < 0 ? 0 : (bin > 5 ? 5 : bin);
    float tt = v * 6.0f - 1.0f;
    int li = (int)tt;                            // trunc toward zero, matches astype(int32)
    li = li < 0 ? 0 : (li > 5 ? 5 : li);
#pragma unroll
    for (int j = 0; j < 6; j++) {
      unsigned long long mb = __ballot(bin == j);
      unsigned long long ml = __ballot(li == j);
      if (lane == j) cnt += (unsigned)__popcll(mb);
      if (lane == 6 + j) cnt += (unsigned)__popcll(ml);
    }
  }
  if (lane < 12) atomicAdd(&sh[lane], cnt);
  __syncthreads();
  if (threadIdx.x < 12) hist[12 * b + threadIdx.x] = sh[threadIdx.x];
}

// ---------------- K3: per-channel 7-entry LUT ----------------
// LUT[0..5] = interior pixel contribution by lut-index; LUT[6] = border pixel contribution.
__global__ void k_lut(Meta m, const float* cstats, const unsigned* hist, float* lutg, int nch) {
  int b = blockIdx.x * blockDim.x + threadIdx.x;
  if (b >= nch) return;
  int t = findSeg(m.chanOff, b);
  int cl = b - m.chanOff[t];
  int H = m.H[t], W = m.W[t], HW = H * W;
  float fHW = (float)HW;
  int nb = 2 * (H + W) - 4;  // border pixel count
  float mn = cstats[2 * b], mx = cstats[2 * b + 1];
  float d = mx - mn;
  float invd = d > 0.f ? 1.0f / d : 0.f;
  unsigned hh[12];
  for (int j = 0; j < 12; j++) hh[j] = hist[12 * b + j];
  float hl[6];
  for (int j = 0; j < 6; j++) hl[j] = -logf((float)hh[j] / fHW + 1e-4f);
  // dst stats over all pixels (dst value = hl[li], counts = hh[6+li])
  float mn2 = INFINITY, mx2 = -INFINITY, sum2 = 0.f;
  for (int j = 0; j < 6; j++) {
    unsigned cc = hh[6 + j];
    if (cc) { mn2 = fminf(mn2, hl[j]); mx2 = fmaxf(mx2, hl[j]); sum2 += (float)cc * hl[j]; }
  }
  float d2 = mx2 - mn2;
  float RL[6];  // r_c value per lut-index: dst_norm * (1-mean_norm)^2
  if (d2 > 0.f) {
    float meanN = (sum2 / fHW - mn2) / d2;
    float w = 1.0f - meanN; w *= w;   // max_norm == 1 exactly
    for (int j = 0; j < 6; j++) RL[j] = (hl[j] - mn2) / d2 * w;
  } else {
    for (int j = 0; j < 6; j++) RL[j] = 0.f;
  }
  // lut-index of border pixels (masked value 0)
  float vb = (0.f - mn) * invd * 256.0f;
  float ttb = vb * 6.0f - 1.0f;
  int lib = (int)ttb;
  lib = lib < 0 ? 0 : (lib > 5 ? 5 : lib);
  float LUT[7];
  if (cl == 0) {
    // p0 = _ponder(r0, (0,1)) over ALL pixels (no extra border mask)
    float mnr = INFINITY, mxr = -INFINITY, sumr = 0.f;
    for (int j = 0; j < 6; j++) {
      unsigned cc = hh[6 + j];
      if (cc) { mnr = fminf(mnr, RL[j]); mxr = fmaxf(mxr, RL[j]); sumr += (float)cc * RL[j]; }
    }
    float dr = mxr - mnr;
    if (dr > 0.f) {
      float meanr = sumr / fHW;
      float wp = mxr - meanr; wp *= wp;
      for (int j = 0; j < 6; j++) LUT[j] = (RL[j] - mnr) / dr * wp;
      LUT[6] = LUT[lib];
    } else {
      for (int j = 0; j < 7; j++) LUT[j] = 0.f;
    }
  } else {
    // rest_c = r_c * border_mask; stats include border zeros
    float mnr = 0.f, mxr = 0.f, sumr = 0.f;
    for (int j = 0; j < 6; j++) {
      int cc = (int)hh[6 + j] - (j == lib ? nb : 0);
      if (cc > 0) { mnr = fminf(mnr, RL[j]); mxr = fmaxf(mxr, RL[j]); sumr += (float)cc * RL[j]; }
    }
    float dr = mxr - mnr;
    if (dr > 0.f) {
      float meanr = sumr / fHW;
      float wp = mxr - meanr; wp *= wp;
      for (int j = 0; j < 6; j++) LUT[j] = (RL[j] - mnr) / dr * wp;
      LUT[6] = (0.f - mnr) / dr * wp;   // border (value 0) after norm
    } else {
      for (int j = 0; j < 7; j++) LUT[j] = 0.f;
    }
  }
  float* o = lutg + (size_t)b * 9;
  for (int j = 0; j < 7; j++) o[j] = LUT[j];
  o[7] = mn; o[8] = invd;
}

// ---------------- K4: per-pixel p map (sum LUT over channels) ----------------
__global__ __launch_bounds__(256) void k_pmap(Meta m, const float* lutg, float* pmaps) {
  __shared__ float sLut[512 * 8];
  __shared__ float sMn[512];
  __shared__ float sInv[512];
  int b = blockIdx.x;
  int t = findSeg(m.blkOff, b);
  int C = m.C[t], H = m.H[t], W = m.W[t], HW = H * W;
  int c0 = m.chanOff[t];
  for (int i = threadIdx.x; i < C; i += 256) {
    const float* L = lutg + (size_t)(c0 + i) * 9;
#pragma unroll
    for (int j = 0; j < 7; j++) sLut[i * 8 + j] = L[j];
    sMn[i] = L[7]; sInv[i] = L[8];
  }
  __syncthreads();
  int pix = (b - m.blkOff[t]) * 256 + threadIdx.x;
  if (pix >= HW) return;
  int h = pix / W, w = pix - h * W;
  const float* xb = m.x[t] + pix;
  float p = 0.f;
  if (h == 0 || h == H - 1 || w == 0 || w == W - 1) {
    for (int c = 0; c < C; c++) p += sLut[c * 8 + 6];
  } else {
    for (int c = 0; c < C; c++) {
      float xv = xb[(size_t)c * HW];
      float v = (xv - sMn[c]) * sInv[c] * 256.0f;
      float tt = v * 6.0f - 1.0f;
      int li = (int)tt;
      li = li < 0 ? 0 : (li > 5 ? 5 : li);
      p += sLut[c * 8 + li];
    }
  }
  pmaps[m.pixOff[t] + pix] = p;
}

// ---------------- K4b: per-tensor p min/max ----------------
__global__ __launch_bounds__(256) void k_pstats(Meta m, const float* pmaps, float* pstats) {
  int t = blockIdx.x;
  int HW = m.H[t] * m.W[t];
  const float* p = pmaps + m.pixOff[t];
  float mn = INFINITY, mx = -INFINITY;
  for (int i = threadIdx.x; i < HW; i += 256) {
    float v = p[i]; mn = fminf(mn, v); mx = fmaxf(mx, v);
  }
#pragma unroll
  for (int o = 32; o > 0; o >>= 1) {
    mn = fminf(mn, __shfl_down(mn, o));
    mx = fmaxf(mx, __shfl_down(mx, o));
  }
  __shared__ float smn[4], smx[4];
  int wid = threadIdx.x >> 6;
  if ((threadIdx.x & 63) == 0) { smn[wid] = mn; smx[wid] = mx; }
  __syncthreads();
  if (threadIdx.x == 0) {
    for (int i = 1; i < 4; i++) { mn = fminf(mn, smn[i]); mx = fmaxf(mx, smx[i]); }
    pstats[2 * t] = mn; pstats[2 * t + 1] = mx;
  }
}

// ---------------- K5: bilinear resize to 240x240 with norm folded in ----------------
__global__ __launch_bounds__(256) void k_resize(Meta m, const float* pmaps, const float* pstats, float* mmaps) {
  int t = blockIdx.x / 225;
  int pix = (blockIdx.x % 225) * 256 + threadIdx.x;
  if (pix >= RHW) return;
  int H = m.H[t], W = m.W[t];
  const float* p = pmaps + m.pixOff[t];
  float mn = pstats[2 * t], mx = pstats[2 * t + 1];
  float d = mx - mn;
  float a = d > 0.f ? 1.0f / d : 0.f;
  int oy = pix / 240, ox = pix - oy * 240;
  float hs = (float)((double)H / 240.0);
  float wsc = (float)((double)W / 240.0);
  float sy = ((float)oy + 0.5f) * hs - 0.5f;
  float sx = ((float)ox + 0.5f) * wsc - 0.5f;
  float fy0 = floorf(sy), fx0 = floorf(sx);
  float fy = sy - fy0, fx = sx - fx0;
  int iy0 = (int)fy0, ix0 = (int)fx0;
  int y0 = iy0 < 0 ? 0 : (iy0 > H - 1 ? H - 1 : iy0);
  int y1 = iy0 + 1 < 0 ? 0 : (iy0 + 1 > H - 1 ? H - 1 : iy0 + 1);
  int x0 = ix0 < 0 ? 0 : (ix0 > W - 1 ? W - 1 : ix0);
  int x1 = ix0 + 1 < 0 ? 0 : (ix0 + 1 > W - 1 ? W - 1 : ix0 + 1);
  float v00 = p[y0 * W + x0], v01 = p[y0 * W + x1];
  float v10 = p[y1 * W + x0], v11 = p[y1 * W + x1];
  float r = (1.f - fy) * ((1.f - fx) * v00 + fx * v01) + fy * ((1.f - fx) * v10 + fx * v11);
  float mv = d > 0.f ? (r - mn) * a : 0.f;
  mmaps[(size_t)t * RHW + pix] = mv;
}

// ---------------- K5b: per-tensor resized-map min/max/sum ----------------
__global__ __launch_bounds__(256) void k_mstats(const float* mmaps, float* mstats) {
  int t = blockIdx.x;
  const float* p = mmaps + (size_t)t * RHW;
  float mn = INFINITY, mx = -INFINITY, sm = 0.f;
  for (int i = threadIdx.x; i < RHW; i += 256) {
    float v = p[i]; mn = fminf(mn, v); mx = fmaxf(mx, v); sm += v;
  }
#pragma unroll
  for (int o = 32; o > 0; o >>= 1) {
    mn = fminf(mn, __shfl_down(mn, o));
    mx = fmaxf(mx, __shfl_down(mx, o));
    sm += __shfl_down(sm, o);
  }
  __shared__ float smn[4], smx[4], ssm[4];
  int wid = threadIdx.x >> 6;
  if ((threadIdx.x & 63) == 0) { smn[wid] = mn; smx[wid] = mx; ssm[wid] = sm; }
  __syncthreads();
  if (threadIdx.x == 0) {
    for (int i = 1; i < 4; i++) { mn = fminf(mn, smn[i]); mx = fmaxf(mx, smx[i]); sm += ssm[i]; }
    mstats[3 * t] = mn; mstats[3 * t + 1] = mx; mstats[3 * t + 2] = sm;
  }
}

// ---------------- K6: fuse group (sum of ponders) ----------------
__global__ __launch_bounds__(256) void k_fuse(const float* mmaps, const float* mstats, float* fusedm) {
  int g = blockIdx.x / 225;
  int pix = (blockIdx.x % 225) * 256 + threadIdx.x;
  if (pix >= RHW) return;
  const int gs[6] = {0, 2, 4, 7, 10, 13};
  float acc = 0.f;
  for (int t = gs[g]; t < gs[g + 1]; t++) {
    float mn = mstats[3 * t], mx = mstats[3 * t + 1], sm = mstats[3 * t + 2];
    float d = mx - mn;
    if (d > 0.f) {
      float mean = sm * (1.0f / 57600.0f);
      float w = mx - mean; w *= w;
      acc += (mmaps[(size_t)t * RHW + pix] - mn) / d * w;
    }
  }
  fusedm[(size_t)g * RHW + pix] = acc;
}

// ---------------- K6b: per-group fused min/max ----------------
__global__ __launch_bounds__(256) void k_fstats(const float* fusedm, float* fstats) {
  int g = blockIdx.x;
  const float* p = fusedm + (size_t)g * RHW;
  float mn = INFINITY, mx = -INFINITY;
  for (int i = threadIdx.x; i < RHW; i += 256) {
    float v = p[i]; mn = fminf(mn, v); mx = fmaxf(mx, v);
  }
#pragma unroll
  for (int o = 32; o > 0; o >>= 1) {
    mn = fminf(mn, __shfl_down(mn, o));
    mx = fmaxf(mx, __shfl_down(mx, o));
  }
  __shared__ float smn[4], smx[4];
  int wid = threadIdx.x >> 6;
  if ((threadIdx.x & 63) == 0) { smn[wid] = mn; smx[wid] = mx; }
  __syncthreads();
  if (threadIdx.x == 0) {
    for (int i = 1; i < 4; i++) { mn = fminf(mn, smn[i]); mx = fmaxf(mx, smx[i]); }
    fstats[2 * g] = mn; fstats[2 * g + 1] = mx;
  }
}

// ---------------- K7: final outputs ----------------
__global__ __launch_bounds__(256) void k_out(const float* fusedm, const float* fstats, float* out) {
  int pix = blockIdx.x * 256 + threadIdx.x;
  if (pix >= RHW) return;
  float acc = 0.f;
  float* out2 = out + RHW;
#pragma unroll
  for (int g = 0; g < 5; g++) {
    float mn = fstats[2 * g], mx = fstats[2 * g + 1];
    float d = mx - mn;
    float v = d > 0.f ? (fusedm[(size_t)g * RHW + pix] - mn) / d * 256.0f : 0.f;
    out2[(size_t)pix * 5 + g] = v;
    acc += v;
  }
  out[pix] = acc;
}

extern "C" void kernel_launch(void* const* d_in, const int* in_sizes, int n_in,
                              void* d_out, int out_size, void* d_ws, size_t ws_size,
                              hipStream_t stream) {
  static const int Cs[NT] = {64, 64, 128, 128, 256, 256, 256, 512, 512, 512, 512, 512, 512};
  static const int Hs[NT] = {224, 224, 112, 112, 56, 56, 56, 28, 28, 28, 14, 14, 14};
  Meta m;
  int co = 0, po = 0, bo = 0;
  for (int t = 0; t < NT; t++) {
    m.x[t] = (const float*)d_in[t];
    m.C[t] = Cs[t]; m.H[t] = Hs[t]; m.W[t] = Hs[t];
    m.chanOff[t] = co; co += Cs[t];
    m.pixOff[t] = po; po += Hs[t] * Hs[t];
    m.blkOff[t] = bo; bo += (Hs[t] * Hs[t] + 255) / 256;
  }
  m.chanOff[NT] = co; m.pixOff[NT] = po; m.blkOff[NT] = bo;

  char* ws = (char*)d_ws;
  float* cstats = (float*)ws; ws += (size_t)co * 2 * sizeof(float);
  unsigned* hist = (unsigned*)ws; ws += (size_t)co * 12 * sizeof(unsigned);
  float* lutg = (float*)ws; ws += (size_t)co * 9 * sizeof(float);
  float* pmaps = (float*)ws; ws += (size_t)po * sizeof(float);
  float* pstats = (float*)ws; ws += (size_t)NT * 2 * sizeof(float);
  float* mmaps = (float*)ws; ws += (size_t)NT * RHW * sizeof(float);
  float* mstats = (float*)ws; ws += (size_t)NT * 3 * sizeof(float);
  float* fusedm = (float*)ws; ws += (size_t)5 * RHW * sizeof(float);
  float* fstats = (float*)ws; ws += (size_t)5 * 2 * sizeof(float);

  hipLaunchKernelGGL(k_chan_minmax, dim3(co), dim3(256), 0, stream, m, cstats);
  hipLaunchKernelGGL(k_hist, dim3(co), dim3(256), 0, stream, m, cstats, hist);
  hipLaunchKernelGGL(k_lut, dim3((co + 255) / 256), dim3(256), 0, stream, m, cstats, hist, lutg, co);
  hipLaunchKernelGGL(k_pmap, dim3(bo), dim3(256), 0, stream, m, lutg, pmaps);
  hipLaunchKernelGGL(k_pstats, dim3(NT), dim3(256), 0, stream, m, pmaps, pstats);
  hipLaunchKernelGGL(k_resize, dim3(NT * 225), dim3(256), 0, stream, m, pmaps, pstats, mmaps);
  hipLaunchKernelGGL(k_mstats, dim3(NT), dim3(256), 0, stream, mmaps, mstats);
  hipLaunchKernelGGL(k_fuse, dim3(5 * 225), dim3(256), 0, stream, mmaps, mstats, fusedm);
  hipLaunchKernelGGL(k_fstats, dim3(5), dim3(256), 0, stream, fusedm, fstats);
  hipLaunchKernelGGL(k_out, dim3(225), dim3(256), 0, stream, fusedm, fstats, (float*)d_out);
}

// Round 2
// 161.681 us; speedup vs baseline: 2.5277x; 2.5277x over previous
//
#include <hip/hip_runtime.h>
#include <math.h>

#define NT 13
#define RHW 57600  // 240*240
#define PIXB 8192  // pixels per block for minmax/hist

struct Meta {
  const float* x[NT];
  int C[NT];
  int H[NT];
  int chanOff[NT + 1];
  int pixOff[NT + 1];
  int mmOff[NT + 1];
  int nchMM[NT];
  int pmOff[NT + 1];
  int npcPM[NT];
  int pcOff[NT + 1];
};

// monotone float<->uint encoding (order-preserving) for deterministic atomic min/max
__device__ __forceinline__ unsigned encf(float f) {
  unsigned u = __float_as_uint(f);
  return (u & 0x80000000u) ? ~u : (u | 0x80000000u);
}
__device__ __forceinline__ float decf(unsigned e) {
  unsigned u = (e & 0x80000000u) ? (e & 0x7fffffffu) : ~e;
  return __uint_as_float(u);
}

__device__ __forceinline__ int segOf(const int* off, int b) {
  int t = 0;
  while (t + 1 < NT && b >= off[t + 1]) t++;
  return t;
}

// ---------------- K0: init stats/accumulators ----------------
__global__ __launch_bounds__(256) void k_init(unsigned* cstats, unsigned* hist, unsigned* pstats,
                                              unsigned* msMM, unsigned long long* msum, unsigned* fstats,
                                              unsigned long long* pq, int co, int po) {
  int i = blockIdx.x * 256 + threadIdx.x;
  int stride = gridDim.x * 256;
  for (int k = i; k < po; k += stride) pq[k] = 0ull;
  for (int k = i; k < 12 * co; k += stride) hist[k] = 0u;
  for (int k = i; k < co; k += stride) { cstats[2 * k] = 0xFFFFFFFFu; cstats[2 * k + 1] = 0u; }
  if (i < NT) {
    pstats[2 * i] = 0xFFFFFFFFu; pstats[2 * i + 1] = 0u;
    msMM[2 * i] = 0xFFFFFFFFu;   msMM[2 * i + 1] = 0u;
    msum[i] = 0ull;
  }
  if (i < 5) { fstats[2 * i] = 0xFFFFFFFFu; fstats[2 * i + 1] = 0u; }
}

// ---------------- K1: per-channel interior min/max (chunked) ----------------
template <int HH>
__device__ __forceinline__ void mm_body(const float* __restrict__ ch, int pix0, int pix1, float& mn, float& mx) {
  constexpr int W = HH, H = HH;
  int i40 = pix0 >> 2, i41 = pix1 >> 2;
  for (int i4 = i40 + (int)threadIdx.x; i4 < i41; i4 += 256) {
    float4 v = reinterpret_cast<const float4*>(ch)[i4];
#pragma unroll
    for (int j = 0; j < 4; j++) {
      int idx = i4 * 4 + j;
      int h = idx / W, w = idx - h * W;   // compile-time magic div
      bool ok = h > 0 && h < (H - 1) && w > 0 && w < (W - 1);
      float f = (j == 0) ? v.x : (j == 1) ? v.y : (j == 2) ? v.z : v.w;
      if (ok) { mn = fminf(mn, f); mx = fmaxf(mx, f); }
    }
  }
}

__global__ __launch_bounds__(256) void k_minmax(Meta m, unsigned* cstats) {
  int b = blockIdx.x;
  int t = segOf(m.mmOff, b);
  int local = b - m.mmOff[t];
  int nch = m.nchMM[t];
  int c = local / nch, k = local - c * nch;
  int HW = m.H[t] * m.H[t];
  const float* ch = m.x[t] + (size_t)c * HW;
  int pix0 = k * PIXB, pix1 = min(pix0 + PIXB, HW);
  float mn = INFINITY, mx = -INFINITY;
  switch (m.H[t]) {
    case 224: mm_body<224>(ch, pix0, pix1, mn, mx); break;
    case 112: mm_body<112>(ch, pix0, pix1, mn, mx); break;
    case 56:  mm_body<56>(ch, pix0, pix1, mn, mx); break;
    case 28:  mm_body<28>(ch, pix0, pix1, mn, mx); break;
    default:  mm_body<14>(ch, pix0, pix1, mn, mx); break;
  }
#pragma unroll
  for (int o = 32; o > 0; o >>= 1) {
    mn = fminf(mn, __shfl_down(mn, o));
    mx = fmaxf(mx, __shfl_down(mx, o));
  }
  __shared__ float smn[4], smx[4];
  int wid = threadIdx.x >> 6;
  if ((threadIdx.x & 63) == 0) { smn[wid] = mn; smx[wid] = mx; }
  __syncthreads();
  if (threadIdx.x == 0) {
    for (int i = 1; i < 4; i++) { mn = fminf(mn, smn[i]); mx = fmaxf(mx, smx[i]); }
    int g = m.chanOff[t] + c;
    atomicMin(&cstats[2 * g], encf(mn));
    atomicMax(&cstats[2 * g + 1], encf(mx));
  }
}

// ---------------- K2: per-channel dual 6-bin histograms (interior only, chunked) ----------------
template <int HH>
__device__ __forceinline__ void hist_body(const float* __restrict__ ch, int pix0, int pix1,
                                          float mn, float invd, unsigned* sh) {
  constexpr int W = HH, H = HH;
  int i40 = pix0 >> 2, i41 = pix1 >> 2;
  int nIter = (i41 - i40 + 255) >> 8;
  int lane = threadIdx.x & 63;
  unsigned cnt = 0;
  for (int it = 0; it < nIter; ++it) {
    int i4 = i40 + it * 256 + (int)threadIdx.x;
    bool valid = i4 < i41;
    float4 v = make_float4(0.f, 0.f, 0.f, 0.f);
    if (valid) v = reinterpret_cast<const float4*>(ch)[i4];
    int code[8];
#pragma unroll
    for (int j = 0; j < 4; j++) {
      int idx = i4 * 4 + j;
      int h = idx / W, w = idx - h * W;
      bool ok = valid && h > 0 && h < (H - 1) && w > 0 && w < (W - 1);
      float f = (j == 0) ? v.x : (j == 1) ? v.y : (j == 2) ? v.z : v.w;
      float vv = (f - mn) * invd * 256.0f;
      int bin = (int)(vv * 0.0234375f);             // * (6/256)
      bin = bin < 0 ? 0 : (bin > 5 ? 5 : bin);
      float tt = vv * 6.0f - 1.0f;
      int li = (int)tt;
      li = li < 0 ? 0 : (li > 5 ? 5 : li);
      code[j] = ok ? bin : -1;
      code[4 + j] = ok ? li : -1;
    }
#pragma unroll
    for (int j = 0; j < 4; j++) {
#pragma unroll
      for (int q = 0; q < 6; q++) {
        unsigned long long mb = __ballot(code[j] == q);
        if (lane == q) cnt += (unsigned)__popcll(mb);
        unsigned long long ml = __ballot(code[4 + j] == q);
        if (lane == 6 + q) cnt += (unsigned)__popcll(ml);
      }
    }
  }
  if (lane < 12) atomicAdd(&sh[lane], cnt);
}

__global__ __launch_bounds__(256) void k_hist(Meta m, const unsigned* cstats, unsigned* hist) {
  int b = blockIdx.x;
  int t = segOf(m.mmOff, b);
  int local = b - m.mmOff[t];
  int nch = m.nchMM[t];
  int c = local / nch, k = local - c * nch;
  int HW = m.H[t] * m.H[t];
  const float* ch = m.x[t] + (size_t)c * HW;
  int g = m.chanOff[t] + c;
  float mn = fminf(decf(cstats[2 * g]), 0.f);          // fold border zeros
  float mx = fmaxf(decf(cstats[2 * g + 1]), 0.f);
  float d = mx - mn;
  float invd = d > 0.f ? 1.0f / d : 0.f;
  int pix0 = k * PIXB, pix1 = min(pix0 + PIXB, HW);
  __shared__ unsigned sh[12];
  if (threadIdx.x < 12) sh[threadIdx.x] = 0;
  __syncthreads();
  switch (m.H[t]) {
    case 224: hist_body<224>(ch, pix0, pix1, mn, invd, sh); break;
    case 112: hist_body<112>(ch, pix0, pix1, mn, invd, sh); break;
    case 56:  hist_body<56>(ch, pix0, pix1, mn, invd, sh); break;
    case 28:  hist_body<28>(ch, pix0, pix1, mn, invd, sh); break;
    default:  hist_body<14>(ch, pix0, pix1, mn, invd, sh); break;
  }
  __syncthreads();
  if (threadIdx.x < 12) atomicAdd(&hist[12 * g + threadIdx.x], sh[threadIdx.x]);
}

// ---------------- K3: per-channel 7-entry LUT ----------------
__global__ void k_lut(Meta m, const unsigned* cstats, const unsigned* hist, float* lutg, int nch) {
  int b = blockIdx.x * blockDim.x + threadIdx.x;
  if (b >= nch) return;
  int t = segOf(m.chanOff, b);
  int cl = b - m.chanOff[t];
  int H = m.H[t], W = m.H[t], HW = H * W;
  float fHW = (float)HW;
  int nb = 2 * (H + W) - 4;  // border pixel count
  float mn = fminf(decf(cstats[2 * b]), 0.f);
  float mx = fmaxf(decf(cstats[2 * b + 1]), 0.f);
  float d = mx - mn;
  float invd = d > 0.f ? 1.0f / d : 0.f;
  // lut/bin index of border pixels (masked value 0)
  float vb = (0.f - mn) * invd * 256.0f;
  int bin_b = (int)(vb * 0.0234375f);
  bin_b = bin_b < 0 ? 0 : (bin_b > 5 ? 5 : bin_b);
  float ttb = vb * 6.0f - 1.0f;
  int lib = (int)ttb;
  lib = lib < 0 ? 0 : (lib > 5 ? 5 : lib);
  unsigned hh[12];
  for (int j = 0; j < 12; j++) hh[j] = hist[12 * b + j];
  hh[bin_b] += (unsigned)nb;       // reconstruct full-mask histograms
  hh[6 + lib] += (unsigned)nb;
  float hl[6];
  for (int j = 0; j < 6; j++) hl[j] = -logf((float)hh[j] / fHW + 1e-4f);
  float mn2 = INFINITY, mx2 = -INFINITY, sum2 = 0.f;
  for (int j = 0; j < 6; j++) {
    unsigned cc = hh[6 + j];
    if (cc) { mn2 = fminf(mn2, hl[j]); mx2 = fmaxf(mx2, hl[j]); sum2 += (float)cc * hl[j]; }
  }
  float d2 = mx2 - mn2;
  float RL[6];
  if (d2 > 0.f) {
    float meanN = (sum2 / fHW - mn2) / d2;
    float w = 1.0f - meanN; w *= w;
    for (int j = 0; j < 6; j++) RL[j] = (hl[j] - mn2) / d2 * w;
  } else {
    for (int j = 0; j < 6; j++) RL[j] = 0.f;
  }
  float LUT[7];
  if (cl == 0) {
    float mnr = INFINITY, mxr = -INFINITY, sumr = 0.f;
    for (int j = 0; j < 6; j++) {
      unsigned cc = hh[6 + j];
      if (cc) { mnr = fminf(mnr, RL[j]); mxr = fmaxf(mxr, RL[j]); sumr += (float)cc * RL[j]; }
    }
    float dr = mxr - mnr;
    if (dr > 0.f) {
      float meanr = sumr / fHW;
      float wp = mxr - meanr; wp *= wp;
      for (int j = 0; j < 6; j++) LUT[j] = (RL[j] - mnr) / dr * wp;
      LUT[6] = LUT[lib];
    } else {
      for (int j = 0; j < 7; j++) LUT[j] = 0.f;
    }
  } else {
    float mnr = 0.f, mxr = 0.f, sumr = 0.f;
    for (int j = 0; j < 6; j++) {
      int cc = (int)hh[6 + j] - (j == lib ? nb : 0);
      if (cc > 0) { mnr = fminf(mnr, RL[j]); mxr = fmaxf(mxr, RL[j]); sumr += (float)cc * RL[j]; }
    }
    float dr = mxr - mnr;
    if (dr > 0.f) {
      float meanr = sumr / fHW;
      float wp = mxr - meanr; wp *= wp;
      for (int j = 0; j < 6; j++) LUT[j] = (RL[j] - mnr) / dr * wp;
      LUT[6] = (0.f - mnr) / dr * wp;
    } else {
      for (int j = 0; j < 7; j++) LUT[j] = 0.f;
    }
  }
  float* o = lutg + (size_t)b * 9;
  for (int j = 0; j < 7; j++) o[j] = LUT[j];
  o[7] = mn; o[8] = invd;
}

// ---------------- K4: per-pixel p map, fixed-point accumulate over channel chunks ----------------
template <int HH>
__device__ __forceinline__ void pm_body(const float* __restrict__ X, int cbase, int ncb, int i4lo, int i4hi,
                                        const float* sLut, const float* sMn, const float* sInv,
                                        unsigned long long* __restrict__ Q) {
  constexpr int W = HH, H = HH;
  constexpr int HW = H * W;
  int i4 = i4lo + (int)threadIdx.x;
  if (i4 >= i4hi) return;
  int base = i4 * 4;
  int b0, b1, b2, b3;
  { int idx = base + 0; int h = idx / W, w = idx - h * W; b0 = (h == 0 || h == H - 1 || w == 0 || w == W - 1); }
  { int idx = base + 1; int h = idx / W, w = idx - h * W; b1 = (h == 0 || h == H - 1 || w == 0 || w == W - 1); }
  { int idx = base + 2; int h = idx / W, w = idx - h * W; b2 = (h == 0 || h == H - 1 || w == 0 || w == W - 1); }
  { int idx = base + 3; int h = idx / W, w = idx - h * W; b3 = (h == 0 || h == H - 1 || w == 0 || w == W - 1); }
  float a0 = 0.f, a1 = 0.f, a2 = 0.f, a3 = 0.f;
  const float4* Xp = reinterpret_cast<const float4*>(X + (size_t)cbase * HW);
#pragma unroll 4
  for (int cl = 0; cl < ncb; ++cl) {
    float4 v = Xp[(size_t)cl * (HW / 4) + i4];
    float mnc = sMn[cl], ivc = sInv[cl];
    const float* L = sLut + cl * 8;
    { float vv = (v.x - mnc) * ivc * 256.0f; float tt = vv * 6.0f - 1.0f; int li = (int)tt; li = li < 0 ? 0 : (li > 5 ? 5 : li); a0 += L[b0 ? 6 : li]; }
    { float vv = (v.y - mnc) * ivc * 256.0f; float tt = vv * 6.0f - 1.0f; int li = (int)tt; li = li < 0 ? 0 : (li > 5 ? 5 : li); a1 += L[b1 ? 6 : li]; }
    { float vv = (v.z - mnc) * ivc * 256.0f; float tt = vv * 6.0f - 1.0f; int li = (int)tt; li = li < 0 ? 0 : (li > 5 ? 5 : li); a2 += L[b2 ? 6 : li]; }
    { float vv = (v.w - mnc) * ivc * 256.0f; float tt = vv * 6.0f - 1.0f; int li = (int)tt; li = li < 0 ? 0 : (li > 5 ? 5 : li); a3 += L[b3 ? 6 : li]; }
  }
  atomicAdd(&Q[base + 0], (unsigned long long)((double)a0 * 4294967296.0));
  atomicAdd(&Q[base + 1], (unsigned long long)((double)a1 * 4294967296.0));
  atomicAdd(&Q[base + 2], (unsigned long long)((double)a2 * 4294967296.0));
  atomicAdd(&Q[base + 3], (unsigned long long)((double)a3 * 4294967296.0));
}

__global__ __launch_bounds__(256) void k_pmapQ(Meta m, const float* lutg, unsigned long long* pmapsQ) {
  __shared__ float sLut[64 * 8];
  __shared__ float sMn[64];
  __shared__ float sInv[64];
  int b = blockIdx.x;
  int t = segOf(m.pmOff, b);
  int local = b - m.pmOff[t];
  int npc = m.npcPM[t];
  int cc = local / npc, pc = local - cc * npc;
  int C = m.C[t], HW = m.H[t] * m.H[t];
  int cbase = cc * 64;
  int ncb = min(64, C - cbase);
  for (int i = threadIdx.x; i < ncb; i += 256) {
    const float* L = lutg + (size_t)(m.chanOff[t] + cbase + i) * 9;
#pragma unroll
    for (int j = 0; j < 7; j++) sLut[i * 8 + j] = L[j];
    sLut[i * 8 + 7] = 0.f;
    sMn[i] = L[7]; sInv[i] = L[8];
  }
  __syncthreads();
  int i4lo = pc * 256;
  int i4hi = min(i4lo + 256, HW >> 2);
  unsigned long long* Q = pmapsQ + m.pixOff[t];
  switch (m.H[t]) {
    case 224: pm_body<224>(m.x[t], cbase, ncb, i4lo, i4hi, sLut, sMn, sInv, Q); break;
    case 112: pm_body<112>(m.x[t], cbase, ncb, i4lo, i4hi, sLut, sMn, sInv, Q); break;
    case 56:  pm_body<56>(m.x[t], cbase, ncb, i4lo, i4hi, sLut, sMn, sInv, Q); break;
    case 28:  pm_body<28>(m.x[t], cbase, ncb, i4lo, i4hi, sLut, sMn, sInv, Q); break;
    default:  pm_body<14>(m.x[t], cbase, ncb, i4lo, i4hi, sLut, sMn, sInv, Q); break;
  }
}

// ---------------- K4b: fixed-point -> float + per-tensor min/max ----------------
__global__ __launch_bounds__(256) void k_pconv(Meta m, const unsigned long long* pmapsQ, float* pmaps, unsigned* pstats) {
  int b = blockIdx.x;
  int t = segOf(m.pcOff, b);
  int HW = m.H[t] * m.H[t];
  int i4 = (b - m.pcOff[t]) * 256 + (int)threadIdx.x;
  float mn = INFINITY, mx = -INFINITY;
  if (i4 < (HW >> 2)) {
    size_t off = (size_t)m.pixOff[t] + (size_t)i4 * 4;
    const double inv = 1.0 / 4294967296.0;
    float4 f;
    f.x = (float)((double)pmapsQ[off + 0] * inv);
    f.y = (float)((double)pmapsQ[off + 1] * inv);
    f.z = (float)((double)pmapsQ[off + 2] * inv);
    f.w = (float)((double)pmapsQ[off + 3] * inv);
    *reinterpret_cast<float4*>(pmaps + off) = f;
    mn = fminf(fminf(f.x, f.y), fminf(f.z, f.w));
    mx = fmaxf(fmaxf(f.x, f.y), fmaxf(f.z, f.w));
  }
#pragma unroll
  for (int o = 32; o > 0; o >>= 1) {
    mn = fminf(mn, __shfl_down(mn, o));
    mx = fmaxf(mx, __shfl_down(mx, o));
  }
  __shared__ float smn[4], smx[4];
  int wid = threadIdx.x >> 6;
  if ((threadIdx.x & 63) == 0) { smn[wid] = mn; smx[wid] = mx; }
  __syncthreads();
  if (threadIdx.x == 0) {
    for (int i = 1; i < 4; i++) { mn = fminf(mn, smn[i]); mx = fmaxf(mx, smx[i]); }
    atomicMin(&pstats[2 * t], encf(mn));
    atomicMax(&pstats[2 * t + 1], encf(mx));
  }
}

// ---------------- K5: bilinear resize + norm + fused mstats ----------------
__global__ __launch_bounds__(256) void k_resize(Meta m, const float* pmaps, const unsigned* pstats,
                                                float* mmaps, unsigned* msMM, unsigned long long* msum) {
  int t = blockIdx.x / 225;
  int pix = (blockIdx.x % 225) * 256 + threadIdx.x;  // 225*256 == 57600 exactly
  int H = m.H[t], W = m.H[t];
  const float* p = pmaps + m.pixOff[t];
  float mn = decf(pstats[2 * t]), mx = decf(pstats[2 * t + 1]);
  float d = mx - mn;
  float a = d > 0.f ? 1.0f / d : 0.f;
  int oy = pix / 240, ox = pix - oy * 240;
  float hs = (float)((double)H / 240.0);
  float wsc = (float)((double)W / 240.0);
  float sy = ((float)oy + 0.5f) * hs - 0.5f;
  float sx = ((float)ox + 0.5f) * wsc - 0.5f;
  float fy0 = floorf(sy), fx0 = floorf(sx);
  float fy = sy - fy0, fx = sx - fx0;
  int iy0 = (int)fy0, ix0 = (int)fx0;
  int y0 = iy0 < 0 ? 0 : (iy0 > H - 1 ? H - 1 : iy0);
  int y1 = iy0 + 1 < 0 ? 0 : (iy0 + 1 > H - 1 ? H - 1 : iy0 + 1);
  int x0 = ix0 < 0 ? 0 : (ix0 > W - 1 ? W - 1 : ix0);
  int x1 = ix0 + 1 < 0 ? 0 : (ix0 + 1 > W - 1 ? W - 1 : ix0 + 1);
  float v00 = p[y0 * W + x0], v01 = p[y0 * W + x1];
  float v10 = p[y1 * W + x0], v11 = p[y1 * W + x1];
  float r = (1.f - fy) * ((1.f - fx) * v00 + fx * v01) + fy * ((1.f - fx) * v10 + fx * v11);
  float mv = d > 0.f ? (r - mn) * a : 0.f;
  mmaps[(size_t)t * RHW + pix] = mv;
  float bmn = mv, bmx = mv;
  unsigned long long bq = (unsigned long long)((double)mv * 4294967296.0);
#pragma unroll
  for (int o = 32; o > 0; o >>= 1) {
    bmn = fminf(bmn, __shfl_down(bmn, o));
    bmx = fmaxf(bmx, __shfl_down(bmx, o));
    bq += __shfl_down(bq, o);
  }
  __shared__ float smn[4], smx[4];
  __shared__ unsigned long long sq[4];
  int wid = threadIdx.x >> 6;
  if ((threadIdx.x & 63) == 0) { smn[wid] = bmn; smx[wid] = bmx; sq[wid] = bq; }
  __syncthreads();
  if (threadIdx.x == 0) {
    for (int i = 1; i < 4; i++) { bmn = fminf(bmn, smn[i]); bmx = fmaxf(bmx, smx[i]); bq += sq[i]; }
    atomicMin(&msMM[2 * t], encf(bmn));
    atomicMax(&msMM[2 * t + 1], encf(bmx));
    atomicAdd(&msum[t], bq);
  }
}

// ---------------- K6: fuse group (sum of ponders) + fused fstats ----------------
__global__ __launch_bounds__(256) void k_fuse(const float* mmaps, const unsigned* msMM, const unsigned long long* msum,
                                              float* fusedm, unsigned* fstats) {
  int g = blockIdx.x / 225;
  int pix = (blockIdx.x % 225) * 256 + threadIdx.x;
  const int gs[6] = {0, 2, 4, 7, 10, 13};
  float acc = 0.f;
  for (int t = gs[g]; t < gs[g + 1]; t++) {
    float mn = decf(msMM[2 * t]), mx = decf(msMM[2 * t + 1]);
    float d = mx - mn;
    if (d > 0.f) {
      float mean = (float)((double)msum[t] * (1.0 / 4294967296.0) * (1.0 / 57600.0));
      float w = mx - mean; w *= w;
      acc += (mmaps[(size_t)t * RHW + pix] - mn) / d * w;
    }
  }
  fusedm[(size_t)g * RHW + pix] = acc;
  float bmn = acc, bmx = acc;
#pragma unroll
  for (int o = 32; o > 0; o >>= 1) {
    bmn = fminf(bmn, __shfl_down(bmn, o));
    bmx = fmaxf(bmx, __shfl_down(bmx, o));
  }
  __shared__ float smn[4], smx[4];
  int wid = threadIdx.x >> 6;
  if ((threadIdx.x & 63) == 0) { smn[wid] = bmn; smx[wid] = bmx; }
  __syncthreads();
  if (threadIdx.x == 0) {
    for (int i = 1; i < 4; i++) { bmn = fminf(bmn, smn[i]); bmx = fmaxf(bmx, smx[i]); }
    atomicMin(&fstats[2 * g], encf(bmn));
    atomicMax(&fstats[2 * g + 1], encf(bmx));
  }
}

// ---------------- K7: final outputs ----------------
__global__ __launch_bounds__(256) void k_out(const float* fusedm, const unsigned* fstats, float* out) {
  int pix = blockIdx.x * 256 + threadIdx.x;
  float acc = 0.f;
  float* out2 = out + RHW;
#pragma unroll
  for (int g = 0; g < 5; g++) {
    float mn = decf(fstats[2 * g]), mx = decf(fstats[2 * g + 1]);
    float d = mx - mn;
    float v = d > 0.f ? (fusedm[(size_t)g * RHW + pix] - mn) / d * 256.0f : 0.f;
    out2[(size_t)pix * 5 + g] = v;
    acc += v;
  }
  out[pix] = acc;
}

extern "C" void kernel_launch(void* const* d_in, const int* in_sizes, int n_in,
                              void* d_out, int out_size, void* d_ws, size_t ws_size,
                              hipStream_t stream) {
  static const int Cs[NT] = {64, 64, 128, 128, 256, 256, 256, 512, 512, 512, 512, 512, 512};
  static const int Hs[NT] = {224, 224, 112, 112, 56, 56, 56, 28, 28, 28, 14, 14, 14};
  Meta m;
  int co = 0, po = 0, mmb = 0, pmb = 0, pcb = 0;
  for (int t = 0; t < NT; t++) {
    m.x[t] = (const float*)d_in[t];
    m.C[t] = Cs[t]; m.H[t] = Hs[t];
    int HW = Hs[t] * Hs[t];
    m.chanOff[t] = co; co += Cs[t];
    m.pixOff[t] = po; po += HW;
    m.mmOff[t] = mmb;
    m.nchMM[t] = (HW + PIXB - 1) / PIXB;
    mmb += Cs[t] * m.nchMM[t];
    m.pmOff[t] = pmb;
    m.npcPM[t] = (HW + 1023) / 1024;
    pmb += m.npcPM[t] * ((Cs[t] + 63) / 64);
    m.pcOff[t] = pcb;
    pcb += (HW + 1023) / 1024;
  }
  m.chanOff[NT] = co; m.pixOff[NT] = po; m.mmOff[NT] = mmb; m.pmOff[NT] = pmb; m.pcOff[NT] = pcb;

  size_t off = 0;
  auto a16 = [](size_t x) { return (x + 15) & ~(size_t)15; };
#define WALLOC(var, type, count) type* var = (type*)((char*)d_ws + off); off = a16(off + sizeof(type) * (size_t)(count));
  WALLOC(cstats, unsigned, 2 * co)
  WALLOC(hist, unsigned, 12 * co)
  WALLOC(lutg, float, 9 * co)
  WALLOC(pstats, unsigned, 2 * NT)
  WALLOC(msMM, unsigned, 2 * NT)
  WALLOC(msum, unsigned long long, NT)
  WALLOC(fstats, unsigned, 10)
  WALLOC(pmaps, float, po)
  WALLOC(mmaps, float, NT * RHW)
  WALLOC(fusedm, float, 5 * RHW)
#undef WALLOC
  // pmapsQ (po u64 = 1.10 MB) aliases mmaps (3.0 MB): Q is dead before k_resize writes mmaps.
  unsigned long long* pmapsQ = (unsigned long long*)mmaps;

  hipLaunchKernelGGL(k_init, dim3(512), dim3(256), 0, stream,
                     cstats, hist, pstats, msMM, msum, fstats, pmapsQ, co, po);
  hipLaunchKernelGGL(k_minmax, dim3(mmb), dim3(256), 0, stream, m, cstats);
  hipLaunchKernelGGL(k_hist, dim3(mmb), dim3(256), 0, stream, m, cstats, hist);
  hipLaunchKernelGGL(k_lut, dim3((co + 255) / 256), dim3(256), 0, stream, m, cstats, hist, lutg, co);
  hipLaunchKernelGGL(k_pmapQ, dim3(pmb), dim3(256), 0, stream, m, lutg, pmapsQ);
  hipLaunchKernelGGL(k_pconv, dim3(pcb), dim3(256), 0, stream, m, pmapsQ, pmaps, pstats);
  hipLaunchKernelGGL(k_resize, dim3(NT * 225), dim3(256), 0, stream, m, pmaps, pstats, mmaps, msMM, msum);
  hipLaunchKernelGGL(k_fuse, dim3(5 * 225), dim3(256), 0, stream, mmaps, msMM, msum, fusedm, fstats);
  hipLaunchKernelGGL(k_out, dim3(225), dim3(256), 0, stream, fusedm, fstats, (float*)d_out);
}

// Round 3
// 91.139 us; speedup vs baseline: 4.4842x; 1.7740x over previous
//
#include <hip/hip_runtime.h>
#include <math.h>

#define NT 13
#define RHW 57600  // 240*240
#define PIXB 8192  // pixels per block for minmax/hist

struct Meta {
  const float* x[NT];
  int C[NT];
  int H[NT];
  float hsc[NT];            // (float)((double)H/240.0), host-computed
  int chanOff[NT + 1];
  int pixOff[NT + 1];
  int mmOff[NT + 1];
  int nchMM[NT];
  int pmOff[NT + 1];
  int npcPM[NT];
  int pcOff[NT + 1];
};

// monotone float<->uint encoding (order-preserving) for deterministic atomic min/max
__device__ __forceinline__ unsigned encf(float f) {
  unsigned u = __float_as_uint(f);
  return (u & 0x80000000u) ? ~u : (u | 0x80000000u);
}
__device__ __forceinline__ float decf(unsigned e) {
  unsigned u = (e & 0x80000000u) ? (e & 0x7fffffffu) : ~e;
  return __uint_as_float(u);
}

__device__ __forceinline__ int segOf(const int* off, int b) {
  int t = 0;
  while (t + 1 < NT && b >= off[t + 1]) t++;
  return t;
}

// ---------------- K0: init accumulators ----------------
__global__ __launch_bounds__(256) void k_init(unsigned* cstats, unsigned* hist,
                                              unsigned long long* pq, int co, int po) {
  int i = blockIdx.x * 256 + threadIdx.x;
  int stride = gridDim.x * 256;
  for (int k = i; k < po; k += stride) pq[k] = 0ull;
  for (int k = i; k < 12 * co; k += stride) hist[k] = 0u;
  for (int k = i; k < co; k += stride) { cstats[2 * k] = 0xFFFFFFFFu; cstats[2 * k + 1] = 0u; }
}

// ---------------- K1: per-channel interior min/max (chunked) ----------------
template <int HH>
__device__ __forceinline__ void mm_body(const float* __restrict__ ch, int pix0, int pix1, float& mn, float& mx) {
  constexpr int W = HH, H = HH;
  int i40 = pix0 >> 2, i41 = pix1 >> 2;
  for (int i4 = i40 + (int)threadIdx.x; i4 < i41; i4 += 256) {
    float4 v = reinterpret_cast<const float4*>(ch)[i4];
#pragma unroll
    for (int j = 0; j < 4; j++) {
      int idx = i4 * 4 + j;
      int h = idx / W, w = idx - h * W;   // compile-time magic div
      bool ok = h > 0 && h < (H - 1) && w > 0 && w < (W - 1);
      float f = (j == 0) ? v.x : (j == 1) ? v.y : (j == 2) ? v.z : v.w;
      if (ok) { mn = fminf(mn, f); mx = fmaxf(mx, f); }
    }
  }
}

__global__ __launch_bounds__(256) void k_minmax(Meta m, unsigned* cstats) {
  int b = blockIdx.x;
  int t = segOf(m.mmOff, b);
  int local = b - m.mmOff[t];
  int nch = m.nchMM[t];
  int c = local / nch, k = local - c * nch;
  int HW = m.H[t] * m.H[t];
  const float* ch = m.x[t] + (size_t)c * HW;
  int pix0 = k * PIXB, pix1 = min(pix0 + PIXB, HW);
  float mn = INFINITY, mx = -INFINITY;
  switch (m.H[t]) {
    case 224: mm_body<224>(ch, pix0, pix1, mn, mx); break;
    case 112: mm_body<112>(ch, pix0, pix1, mn, mx); break;
    case 56:  mm_body<56>(ch, pix0, pix1, mn, mx); break;
    case 28:  mm_body<28>(ch, pix0, pix1, mn, mx); break;
    default:  mm_body<14>(ch, pix0, pix1, mn, mx); break;
  }
#pragma unroll
  for (int o = 32; o > 0; o >>= 1) {
    mn = fminf(mn, __shfl_down(mn, o));
    mx = fmaxf(mx, __shfl_down(mx, o));
  }
  __shared__ float smn[4], smx[4];
  int wid = threadIdx.x >> 6;
  if ((threadIdx.x & 63) == 0) { smn[wid] = mn; smx[wid] = mx; }
  __syncthreads();
  if (threadIdx.x == 0) {
    for (int i = 1; i < 4; i++) { mn = fminf(mn, smn[i]); mx = fmaxf(mx, smx[i]); }
    int g = m.chanOff[t] + c;
    atomicMin(&cstats[2 * g], encf(mn));      // cstats lines are spread (2432 channels) — no hot line
    atomicMax(&cstats[2 * g + 1], encf(mx));
  }
}

// ---------------- K2: per-channel dual 6-bin histograms (interior only, chunked) ----------------
template <int HH>
__device__ __forceinline__ void hist_body(const float* __restrict__ ch, int pix0, int pix1,
                                          float mn, float invd, unsigned* sh) {
  constexpr int W = HH, H = HH;
  int i40 = pix0 >> 2, i41 = pix1 >> 2;
  int nIter = (i41 - i40 + 255) >> 8;
  int lane = threadIdx.x & 63;
  unsigned cnt = 0;
  for (int it = 0; it < nIter; ++it) {
    int i4 = i40 + it * 256 + (int)threadIdx.x;
    bool valid = i4 < i41;
    float4 v = make_float4(0.f, 0.f, 0.f, 0.f);
    if (valid) v = reinterpret_cast<const float4*>(ch)[i4];
    int code[8];
#pragma unroll
    for (int j = 0; j < 4; j++) {
      int idx = i4 * 4 + j;
      int h = idx / W, w = idx - h * W;
      bool ok = valid && h > 0 && h < (H - 1) && w > 0 && w < (W - 1);
      float f = (j == 0) ? v.x : (j == 1) ? v.y : (j == 2) ? v.z : v.w;
      float vv = (f - mn) * invd * 256.0f;
      int bin = (int)(vv * 0.0234375f);             // * (6/256)
      bin = bin < 0 ? 0 : (bin > 5 ? 5 : bin);
      float tt = vv * 6.0f - 1.0f;
      int li = (int)tt;
      li = li < 0 ? 0 : (li > 5 ? 5 : li);
      code[j] = ok ? bin : -1;
      code[4 + j] = ok ? li : -1;
    }
#pragma unroll
    for (int j = 0; j < 4; j++) {
#pragma unroll
      for (int q = 0; q < 6; q++) {
        unsigned long long mb = __ballot(code[j] == q);
        if (lane == q) cnt += (unsigned)__popcll(mb);
        unsigned long long ml = __ballot(code[4 + j] == q);
        if (lane == 6 + q) cnt += (unsigned)__popcll(ml);
      }
    }
  }
  if (lane < 12) atomicAdd(&sh[lane], cnt);
}

__global__ __launch_bounds__(256) void k_hist(Meta m, const unsigned* cstats, unsigned* hist) {
  int b = blockIdx.x;
  int t = segOf(m.mmOff, b);
  int local = b - m.mmOff[t];
  int nch = m.nchMM[t];
  int c = local / nch, k = local - c * nch;
  int HW = m.H[t] * m.H[t];
  const float* ch = m.x[t] + (size_t)c * HW;
  int g = m.chanOff[t] + c;
  float mn = fminf(decf(cstats[2 * g]), 0.f);          // fold border zeros
  float mx = fmaxf(decf(cstats[2 * g + 1]), 0.f);
  float d = mx - mn;
  float invd = d > 0.f ? 1.0f / d : 0.f;
  int pix0 = k * PIXB, pix1 = min(pix0 + PIXB, HW);
  __shared__ unsigned sh[12];
  if (threadIdx.x < 12) sh[threadIdx.x] = 0;
  __syncthreads();
  switch (m.H[t]) {
    case 224: hist_body<224>(ch, pix0, pix1, mn, invd, sh); break;
    case 112: hist_body<112>(ch, pix0, pix1, mn, invd, sh); break;
    case 56:  hist_body<56>(ch, pix0, pix1, mn, invd, sh); break;
    case 28:  hist_body<28>(ch, pix0, pix1, mn, invd, sh); break;
    default:  hist_body<14>(ch, pix0, pix1, mn, invd, sh); break;
  }
  __syncthreads();
  if (threadIdx.x < 12) atomicAdd(&hist[12 * g + threadIdx.x], sh[threadIdx.x]);
}

// ---------------- K3: per-channel 7-entry LUT ----------------
__global__ void k_lut(Meta m, const unsigned* cstats, const unsigned* hist, float* lutg, int nch) {
  int b = blockIdx.x * blockDim.x + threadIdx.x;
  if (b >= nch) return;
  int t = segOf(m.chanOff, b);
  int cl = b - m.chanOff[t];
  int H = m.H[t], W = m.H[t], HW = H * W;
  float fHW = (float)HW;
  int nb = 2 * (H + W) - 4;  // border pixel count
  float mn = fminf(decf(cstats[2 * b]), 0.f);
  float mx = fmaxf(decf(cstats[2 * b + 1]), 0.f);
  float d = mx - mn;
  float invd = d > 0.f ? 1.0f / d : 0.f;
  // lut/bin index of border pixels (masked value 0)
  float vb = (0.f - mn) * invd * 256.0f;
  int bin_b = (int)(vb * 0.0234375f);
  bin_b = bin_b < 0 ? 0 : (bin_b > 5 ? 5 : bin_b);
  float ttb = vb * 6.0f - 1.0f;
  int lib = (int)ttb;
  lib = lib < 0 ? 0 : (lib > 5 ? 5 : lib);
  unsigned hh[12];
  for (int j = 0; j < 12; j++) hh[j] = hist[12 * b + j];
  hh[bin_b] += (unsigned)nb;       // reconstruct full-mask histograms
  hh[6 + lib] += (unsigned)nb;
  float hl[6];
  for (int j = 0; j < 6; j++) hl[j] = -logf((float)hh[j] / fHW + 1e-4f);
  float mn2 = INFINITY, mx2 = -INFINITY, sum2 = 0.f;
  for (int j = 0; j < 6; j++) {
    unsigned cc = hh[6 + j];
    if (cc) { mn2 = fminf(mn2, hl[j]); mx2 = fmaxf(mx2, hl[j]); sum2 += (float)cc * hl[j]; }
  }
  float d2 = mx2 - mn2;
  float RL[6];
  if (d2 > 0.f) {
    float meanN = (sum2 / fHW - mn2) / d2;
    float w = 1.0f - meanN; w *= w;
    for (int j = 0; j < 6; j++) RL[j] = (hl[j] - mn2) / d2 * w;
  } else {
    for (int j = 0; j < 6; j++) RL[j] = 0.f;
  }
  float LUT[7];
  if (cl == 0) {
    float mnr = INFINITY, mxr = -INFINITY, sumr = 0.f;
    for (int j = 0; j < 6; j++) {
      unsigned cc = hh[6 + j];
      if (cc) { mnr = fminf(mnr, RL[j]); mxr = fmaxf(mxr, RL[j]); sumr += (float)cc * RL[j]; }
    }
    float dr = mxr - mnr;
    if (dr > 0.f) {
      float meanr = sumr / fHW;
      float wp = mxr - meanr; wp *= wp;
      for (int j = 0; j < 6; j++) LUT[j] = (RL[j] - mnr) / dr * wp;
      LUT[6] = LUT[lib];
    } else {
      for (int j = 0; j < 7; j++) LUT[j] = 0.f;
    }
  } else {
    float mnr = 0.f, mxr = 0.f, sumr = 0.f;
    for (int j = 0; j < 6; j++) {
      int cc = (int)hh[6 + j] - (j == lib ? nb : 0);
      if (cc > 0) { mnr = fminf(mnr, RL[j]); mxr = fmaxf(mxr, RL[j]); sumr += (float)cc * RL[j]; }
    }
    float dr = mxr - mnr;
    if (dr > 0.f) {
      float meanr = sumr / fHW;
      float wp = mxr - meanr; wp *= wp;
      for (int j = 0; j < 6; j++) LUT[j] = (RL[j] - mnr) / dr * wp;
      LUT[6] = (0.f - mnr) / dr * wp;
    } else {
      for (int j = 0; j < 7; j++) LUT[j] = 0.f;
    }
  }
  float* o = lutg + (size_t)b * 9;
  for (int j = 0; j < 7; j++) o[j] = LUT[j];
  o[7] = mn; o[8] = invd;
}

// ---------------- K4: per-pixel p map, fixed-point accumulate over channel chunks ----------------
#define CCH 32
template <int HH>
__device__ __forceinline__ void pm_body(const float* __restrict__ X, int cbase, int ncb, int i4lo, int i4hi,
                                        const float* sLut, const float* sMn, const float* sInv,
                                        unsigned long long* __restrict__ Q) {
  constexpr int W = HH, H = HH;
  constexpr int HW = H * W;
  int i4 = i4lo + (int)threadIdx.x;
  if (i4 >= i4hi) return;
  int base = i4 * 4;
  int b0, b1, b2, b3;
  { int idx = base + 0; int h = idx / W, w = idx - h * W; b0 = (h == 0 || h == H - 1 || w == 0 || w == W - 1); }
  { int idx = base + 1; int h = idx / W, w = idx - h * W; b1 = (h == 0 || h == H - 1 || w == 0 || w == W - 1); }
  { int idx = base + 2; int h = idx / W, w = idx - h * W; b2 = (h == 0 || h == H - 1 || w == 0 || w == W - 1); }
  { int idx = base + 3; int h = idx / W, w = idx - h * W; b3 = (h == 0 || h == H - 1 || w == 0 || w == W - 1); }
  float a0 = 0.f, a1 = 0.f, a2 = 0.f, a3 = 0.f;
  const float4* Xp = reinterpret_cast<const float4*>(X + (size_t)cbase * HW);
#pragma unroll 4
  for (int cl = 0; cl < ncb; ++cl) {
    float4 v = Xp[(size_t)cl * (HW / 4) + i4];
    float mnc = sMn[cl], ivc = sInv[cl];
    const float* L = sLut + cl * 8;
    { float vv = (v.x - mnc) * ivc * 256.0f; float tt = vv * 6.0f - 1.0f; int li = (int)tt; li = li < 0 ? 0 : (li > 5 ? 5 : li); a0 += L[b0 ? 6 : li]; }
    { float vv = (v.y - mnc) * ivc * 256.0f; float tt = vv * 6.0f - 1.0f; int li = (int)tt; li = li < 0 ? 0 : (li > 5 ? 5 : li); a1 += L[b1 ? 6 : li]; }
    { float vv = (v.z - mnc) * ivc * 256.0f; float tt = vv * 6.0f - 1.0f; int li = (int)tt; li = li < 0 ? 0 : (li > 5 ? 5 : li); a2 += L[b2 ? 6 : li]; }
    { float vv = (v.w - mnc) * ivc * 256.0f; float tt = vv * 6.0f - 1.0f; int li = (int)tt; li = li < 0 ? 0 : (li > 5 ? 5 : li); a3 += L[b3 ? 6 : li]; }
  }
  atomicAdd(&Q[base + 0], (unsigned long long)((double)a0 * 4294967296.0));
  atomicAdd(&Q[base + 1], (unsigned long long)((double)a1 * 4294967296.0));
  atomicAdd(&Q[base + 2], (unsigned long long)((double)a2 * 4294967296.0));
  atomicAdd(&Q[base + 3], (unsigned long long)((double)a3 * 4294967296.0));
}

__global__ __launch_bounds__(256) void k_pmapQ(Meta m, const float* lutg, unsigned long long* pmapsQ) {
  __shared__ float sLut[CCH * 8];
  __shared__ float sMn[CCH];
  __shared__ float sInv[CCH];
  int b = blockIdx.x;
  int t = segOf(m.pmOff, b);
  int local = b - m.pmOff[t];
  int npc = m.npcPM[t];
  int cc = local / npc, pc = local - cc * npc;
  int C = m.C[t], HW = m.H[t] * m.H[t];
  int cbase = cc * CCH;
  int ncb = min(CCH, C - cbase);
  for (int i = threadIdx.x; i < ncb; i += 256) {
    const float* L = lutg + (size_t)(m.chanOff[t] + cbase + i) * 9;
#pragma unroll
    for (int j = 0; j < 7; j++) sLut[i * 8 + j] = L[j];
    sLut[i * 8 + 7] = 0.f;
    sMn[i] = L[7]; sInv[i] = L[8];
  }
  __syncthreads();
  int i4lo = pc * 256;
  int i4hi = min(i4lo + 256, HW >> 2);
  unsigned long long* Q = pmapsQ + m.pixOff[t];
  switch (m.H[t]) {
    case 224: pm_body<224>(m.x[t], cbase, ncb, i4lo, i4hi, sLut, sMn, sInv, Q); break;
    case 112: pm_body<112>(m.x[t], cbase, ncb, i4lo, i4hi, sLut, sMn, sInv, Q); break;
    case 56:  pm_body<56>(m.x[t], cbase, ncb, i4lo, i4hi, sLut, sMn, sInv, Q); break;
    case 28:  pm_body<28>(m.x[t], cbase, ncb, i4lo, i4hi, sLut, sMn, sInv, Q); break;
    default:  pm_body<14>(m.x[t], cbase, ncb, i4lo, i4hi, sLut, sMn, sInv, Q); break;
  }
}

// ---------------- K4b: fixed-point -> float + per-chunk min/max partials ----------------
__global__ __launch_bounds__(256) void k_pconv(Meta m, const unsigned long long* pmapsQ, float* pmaps, float* ppart) {
  int b = blockIdx.x;
  int t = segOf(m.pcOff, b);
  int HW = m.H[t] * m.H[t];
  int chunk = b - m.pcOff[t];
  int i4 = chunk * 256 + (int)threadIdx.x;
  float mn = INFINITY, mx = -INFINITY;
  if (i4 < (HW >> 2)) {
    size_t off = (size_t)m.pixOff[t] + (size_t)i4 * 4;
    const double inv = 1.0 / 4294967296.0;
    float4 f;
    f.x = (float)((double)pmapsQ[off + 0] * inv);
    f.y = (float)((double)pmapsQ[off + 1] * inv);
    f.z = (float)((double)pmapsQ[off + 2] * inv);
    f.w = (float)((double)pmapsQ[off + 3] * inv);
    *reinterpret_cast<float4*>(pmaps + off) = f;
    mn = fminf(fminf(f.x, f.y), fminf(f.z, f.w));
    mx = fmaxf(fmaxf(f.x, f.y), fmaxf(f.z, f.w));
  }
#pragma unroll
  for (int o = 32; o > 0; o >>= 1) {
    mn = fminf(mn, __shfl_down(mn, o));
    mx = fmaxf(mx, __shfl_down(mx, o));
  }
  __shared__ float smn[4], smx[4];
  int wid = threadIdx.x >> 6;
  if ((threadIdx.x & 63) == 0) { smn[wid] = mn; smx[wid] = mx; }
  __syncthreads();
  if (threadIdx.x == 0) {
    for (int i = 1; i < 4; i++) { mn = fminf(mn, smn[i]); mx = fmaxf(mx, smx[i]); }
    ppart[2 * b] = mn; ppart[2 * b + 1] = mx;
  }
}

// ---------------- K5: bilinear resize + norm; per-block (mn,mx,sum) partials ----------------
__global__ __launch_bounds__(256) void k_resize(Meta m, const float* pmaps, const float* ppart,
                                                float* mmaps, float* rpart) {
  __shared__ float sMnT, sInvT;
  int t = blockIdx.x / 225;
  int blk = blockIdx.x % 225;
  int wid = threadIdx.x >> 6, lane = threadIdx.x & 63;
  // wave 0: reduce this tensor's pconv partials (deterministic, redundant per block)
  if (wid == 0) {
    int n = m.pcOff[t + 1] - m.pcOff[t];      // <= 49 chunks
    const float* pp = ppart + (size_t)m.pcOff[t] * 2;
    float mn = INFINITY, mx = -INFINITY;
    if (lane < n) { mn = pp[2 * lane]; mx = pp[2 * lane + 1]; }
#pragma unroll
    for (int o = 32; o > 0; o >>= 1) {
      mn = fminf(mn, __shfl_down(mn, o));
      mx = fmaxf(mx, __shfl_down(mx, o));
    }
    if (lane == 0) {
      float d = mx - mn;
      sMnT = mn; sInvT = d > 0.f ? 1.0f / d : 0.f;
    }
  }
  __syncthreads();
  int pix = blk * 256 + threadIdx.x;  // 225*256 == 57600 exactly
  int H = m.H[t], W = m.H[t];
  const float* p = pmaps + m.pixOff[t];
  float mn = sMnT, a = sInvT;
  int oy = pix / 240, ox = pix - oy * 240;
  float hs = m.hsc[t];
  float sy = ((float)oy + 0.5f) * hs - 0.5f;
  float sx = ((float)ox + 0.5f) * hs - 0.5f;
  float fy0 = floorf(sy), fx0 = floorf(sx);
  float fy = sy - fy0, fx = sx - fx0;
  int iy0 = (int)fy0, ix0 = (int)fx0;
  int y0 = iy0 < 0 ? 0 : (iy0 > H - 1 ? H - 1 : iy0);
  int y1 = iy0 + 1 < 0 ? 0 : (iy0 + 1 > H - 1 ? H - 1 : iy0 + 1);
  int x0 = ix0 < 0 ? 0 : (ix0 > W - 1 ? W - 1 : ix0);
  int x1 = ix0 + 1 < 0 ? 0 : (ix0 + 1 > W - 1 ? W - 1 : ix0 + 1);
  float v00 = p[y0 * W + x0], v01 = p[y0 * W + x1];
  float v10 = p[y1 * W + x0], v11 = p[y1 * W + x1];
  float r = (1.f - fy) * ((1.f - fx) * v00 + fx * v01) + fy * ((1.f - fx) * v10 + fx * v11);
  float mv = (r - mn) * a;            // a==0 encodes d<=0 -> mv = 0... (r-mn)*0 == 0
  mmaps[(size_t)t * RHW + pix] = mv;
  float bmn = mv, bmx = mv, bsm = mv;
#pragma unroll
  for (int o = 32; o > 0; o >>= 1) {
    bmn = fminf(bmn, __shfl_down(bmn, o));
    bmx = fmaxf(bmx, __shfl_down(bmx, o));
    bsm += __shfl_down(bsm, o);
  }
  __shared__ float smn[4], smx[4], ssm[4];
  if ((threadIdx.x & 63) == 0) { smn[wid] = bmn; smx[wid] = bmx; ssm[wid] = bsm; }
  __syncthreads();
  if (threadIdx.x == 0) {
    for (int i = 1; i < 4; i++) { bmn = fminf(bmn, smn[i]); bmx = fmaxf(bmx, smx[i]); bsm += ssm[i]; }
    float* rp = rpart + ((size_t)t * 225 + blk) * 3;
    rp[0] = bmn; rp[1] = bmx; rp[2] = bsm;
  }
}

// ---------------- K6: fuse group (inline partial reduce, no atomics) ----------------
__global__ __launch_bounds__(256) void k_fuse(const float* mmaps, const float* rpart,
                                              float* fusedm, float* fpart) {
  __shared__ float sMn[3], sD[3], sW[3];
  int g = blockIdx.x / 225;
  int blk = blockIdx.x % 225;
  const int gs[6] = {0, 2, 4, 7, 10, 13};
  int nt = gs[g + 1] - gs[g];
  int wid = threadIdx.x >> 6, lane = threadIdx.x & 63;
  if (wid < nt) {
    int t = gs[g] + wid;
    const float* rp = rpart + (size_t)t * 225 * 3;
    float mn = INFINITY, mx = -INFINITY, sm = 0.f;
    for (int i = lane; i < 225; i += 64) {
      mn = fminf(mn, rp[3 * i]); mx = fmaxf(mx, rp[3 * i + 1]); sm += rp[3 * i + 2];
    }
#pragma unroll
    for (int o = 32; o > 0; o >>= 1) {
      mn = fminf(mn, __shfl_down(mn, o));
      mx = fmaxf(mx, __shfl_down(mx, o));
      sm += __shfl_down(sm, o);
    }
    if (lane == 0) {
      float d = mx - mn;
      if (d > 0.f) {
        float mean = sm * (1.0f / 57600.0f);
        float w = mx - mean; w *= w;
        sMn[wid] = mn; sD[wid] = d; sW[wid] = w;
      } else {
        sMn[wid] = 0.f; sD[wid] = 0.f; sW[wid] = 0.f;
      }
    }
  }
  __syncthreads();
  int pix = blk * 256 + threadIdx.x;
  float acc = 0.f;
  for (int k = 0; k < nt; k++) {
    int t = gs[g] + k;
    if (sD[k] > 0.f) acc += (mmaps[(size_t)t * RHW + pix] - sMn[k]) / sD[k] * sW[k];
  }
  fusedm[(size_t)g * RHW + pix] = acc;
  float bmn = acc, bmx = acc;
#pragma unroll
  for (int o = 32; o > 0; o >>= 1) {
    bmn = fminf(bmn, __shfl_down(bmn, o));
    bmx = fmaxf(bmx, __shfl_down(bmx, o));
  }
  __shared__ float smn[4], smx[4];
  if ((threadIdx.x & 63) == 0) { smn[wid] = bmn; smx[wid] = bmx; }
  __syncthreads();
  if (threadIdx.x == 0) {
    for (int i = 1; i < 4; i++) { bmn = fminf(bmn, smn[i]); bmx = fmaxf(bmx, smx[i]); }
    float* fp = fpart + ((size_t)g * 225 + blk) * 2;
    fp[0] = bmn; fp[1] = bmx;
  }
}

// ---------------- K7: final outputs (inline fstats reduce) ----------------
__global__ __launch_bounds__(256) void k_out(const float* fusedm, const float* fpart, float* out) {
  __shared__ float fmn[5], finv[5];
  int wid = threadIdx.x >> 6, lane = threadIdx.x & 63;
  for (int g = wid; g < 5; g += 4) {
    const float* fp = fpart + (size_t)g * 225 * 2;
    float mn = INFINITY, mx = -INFINITY;
    for (int i = lane; i < 225; i += 64) {
      mn = fminf(mn, fp[2 * i]); mx = fmaxf(mx, fp[2 * i + 1]);
    }
#pragma unroll
    for (int o = 32; o > 0; o >>= 1) {
      mn = fminf(mn, __shfl_down(mn, o));
      mx = fmaxf(mx, __shfl_down(mx, o));
    }
    if (lane == 0) {
      float d = mx - mn;
      fmn[g] = mn; finv[g] = d > 0.f ? 256.0f / d : 0.f;
    }
  }
  __syncthreads();
  int pix = blockIdx.x * 256 + threadIdx.x;
  float acc = 0.f;
  float* out2 = out + RHW;
#pragma unroll
  for (int g = 0; g < 5; g++) {
    float v = (fusedm[(size_t)g * RHW + pix] - fmn[g]) * finv[g];
    out2[(size_t)pix * 5 + g] = v;
    acc += v;
  }
  out[pix] = acc;
}

extern "C" void kernel_launch(void* const* d_in, const int* in_sizes, int n_in,
                              void* d_out, int out_size, void* d_ws, size_t ws_size,
                              hipStream_t stream) {
  static const int Cs[NT] = {64, 64, 128, 128, 256, 256, 256, 512, 512, 512, 512, 512, 512};
  static const int Hs[NT] = {224, 224, 112, 112, 56, 56, 56, 28, 28, 28, 14, 14, 14};
  Meta m;
  int co = 0, po = 0, mmb = 0, pmb = 0, pcb = 0;
  for (int t = 0; t < NT; t++) {
    m.x[t] = (const float*)d_in[t];
    m.C[t] = Cs[t]; m.H[t] = Hs[t];
    m.hsc[t] = (float)((double)Hs[t] / 240.0);
    int HW = Hs[t] * Hs[t];
    m.chanOff[t] = co; co += Cs[t];
    m.pixOff[t] = po; po += HW;
    m.mmOff[t] = mmb;
    m.nchMM[t] = (HW + PIXB - 1) / PIXB;
    mmb += Cs[t] * m.nchMM[t];
    m.pmOff[t] = pmb;
    m.npcPM[t] = (HW + 1023) / 1024;
    pmb += m.npcPM[t] * ((Cs[t] + CCH - 1) / CCH);
    m.pcOff[t] = pcb;
    pcb += (HW + 1023) / 1024;
  }
  m.chanOff[NT] = co; m.pixOff[NT] = po; m.mmOff[NT] = mmb; m.pmOff[NT] = pmb; m.pcOff[NT] = pcb;

  size_t off = 0;
  auto a16 = [](size_t x) { return (x + 15) & ~(size_t)15; };
#define WALLOC(var, type, count) type* var = (type*)((char*)d_ws + off); off = a16(off + sizeof(type) * (size_t)(count));
  WALLOC(cstats, unsigned, 2 * co)
  WALLOC(hist, unsigned, 12 * co)
  WALLOC(lutg, float, 9 * co)
  WALLOC(ppart, float, 2 * pcb)
  WALLOC(rpart, float, NT * 225 * 3)
  WALLOC(fpart, float, 5 * 225 * 2)
  WALLOC(pmaps, float, po)
  WALLOC(mmaps, float, NT * RHW)
  WALLOC(fusedm, float, 5 * RHW)
#undef WALLOC
  // pmapsQ (po u64 = 1.10 MB) aliases mmaps (3.0 MB): Q is dead before k_resize writes mmaps.
  unsigned long long* pmapsQ = (unsigned long long*)mmaps;

  hipLaunchKernelGGL(k_init, dim3(512), dim3(256), 0, stream, cstats, hist, pmapsQ, co, po);
  hipLaunchKernelGGL(k_minmax, dim3(mmb), dim3(256), 0, stream, m, cstats);
  hipLaunchKernelGGL(k_hist, dim3(mmb), dim3(256), 0, stream, m, cstats, hist);
  hipLaunchKernelGGL(k_lut, dim3((co + 255) / 256), dim3(256), 0, stream, m, cstats, hist, lutg, co);
  hipLaunchKernelGGL(k_pmapQ, dim3(pmb), dim3(256), 0, stream, m, lutg, pmapsQ);
  hipLaunchKernelGGL(k_pconv, dim3(pcb), dim3(256), 0, stream, m, pmapsQ, pmaps, ppart);
  hipLaunchKernelGGL(k_resize, dim3(NT * 225), dim3(256), 0, stream, m, pmaps, ppart, mmaps, rpart);
  hipLaunchKernelGGL(k_fuse, dim3(5 * 225), dim3(256), 0, stream, mmaps, rpart, fusedm, fpart);
  hipLaunchKernelGGL(k_out, dim3(225), dim3(256), 0, stream, fusedm, fpart, (float*)d_out);
}

// Round 4
// 77.436 us; speedup vs baseline: 5.2777x; 1.1770x over previous
//
#include <hip/hip_runtime.h>
#include <math.h>

#define NT 13
#define RHW 57600  // 240*240
#define PIXB 8192  // pixels per chunk for minmax/hist

struct Meta {
  const float* x[NT];
  int C[NT];
  int H[NT];
  float hsc[NT];            // (float)((double)H/240.0), host-computed
  int pixOff[NT + 1];
  int mmOff[NT + 1];        // (channel,chunk) partial offsets
  int nchMM[NT];            // chunks per channel
  int pmOff[NT + 1];        // pmap block offsets (256 px per block)
};

__device__ __forceinline__ int segOf(const int* off, int b) {
  int t = 0;
  while (t + 1 < NT && b >= off[t + 1]) t++;
  return t;
}

// ---------------- K1: per-(channel,chunk) interior min/max partials ----------------
template <int HH>
__device__ __forceinline__ void mm_body(const float* __restrict__ ch, int pix0, int pix1, float& mn, float& mx) {
  constexpr int W = HH, H = HH;
  int i40 = pix0 >> 2, i41 = pix1 >> 2;
  for (int i4 = i40 + (int)threadIdx.x; i4 < i41; i4 += 256) {
    float4 v = reinterpret_cast<const float4*>(ch)[i4];
#pragma unroll
    for (int j = 0; j < 4; j++) {
      int idx = i4 * 4 + j;
      int h = idx / W, w = idx - h * W;   // compile-time magic div
      bool ok = h > 0 && h < (H - 1) && w > 0 && w < (W - 1);
      float f = (j == 0) ? v.x : (j == 1) ? v.y : (j == 2) ? v.z : v.w;
      if (ok) { mn = fminf(mn, f); mx = fmaxf(mx, f); }
    }
  }
}

__global__ __launch_bounds__(256) void k_minmax(Meta m, float* cpart) {
  int b = blockIdx.x;
  int t = segOf(m.mmOff, b);
  int local = b - m.mmOff[t];
  int nch = m.nchMM[t];
  int c = local / nch, k = local - c * nch;
  int HW = m.H[t] * m.H[t];
  const float* ch = m.x[t] + (size_t)c * HW;
  int pix0 = k * PIXB, pix1 = min(pix0 + PIXB, HW);
  float mn = INFINITY, mx = -INFINITY;
  switch (m.H[t]) {
    case 224: mm_body<224>(ch, pix0, pix1, mn, mx); break;
    case 112: mm_body<112>(ch, pix0, pix1, mn, mx); break;
    case 56:  mm_body<56>(ch, pix0, pix1, mn, mx); break;
    case 28:  mm_body<28>(ch, pix0, pix1, mn, mx); break;
    default:  mm_body<14>(ch, pix0, pix1, mn, mx); break;
  }
#pragma unroll
  for (int o = 32; o > 0; o >>= 1) {
    mn = fminf(mn, __shfl_down(mn, o));
    mx = fmaxf(mx, __shfl_down(mx, o));
  }
  __shared__ float smn[4], smx[4];
  int wid = threadIdx.x >> 6;
  if ((threadIdx.x & 63) == 0) { smn[wid] = mn; smx[wid] = mx; }
  __syncthreads();
  if (threadIdx.x == 0) {
    for (int i = 1; i < 4; i++) { mn = fminf(mn, smn[i]); mx = fmaxf(mx, smx[i]); }
    cpart[2 * b] = mn; cpart[2 * b + 1] = mx;
  }
}

// ---------------- K2: per-(channel,chunk) dual 6-bin histogram partials ----------------
// Two u64 accumulators per lane, 6 x 10-bit fields (max 32 counts/lane/chunk -> no overflow).
template <int HH>
__device__ __forceinline__ void hist_body(const float* __restrict__ ch, int pix0, int pix1,
                                          float mn, float invd,
                                          unsigned long long& cbin, unsigned long long& clut) {
  constexpr int W = HH, H = HH;
  int i40 = pix0 >> 2, i41 = pix1 >> 2;
  int nIter = (i41 - i40 + 255) >> 8;
  for (int it = 0; it < nIter; ++it) {
    int i4 = i40 + it * 256 + (int)threadIdx.x;
    bool valid = i4 < i41;
    float4 v = make_float4(0.f, 0.f, 0.f, 0.f);
    if (valid) v = reinterpret_cast<const float4*>(ch)[i4];
#pragma unroll
    for (int j = 0; j < 4; j++) {
      int idx = i4 * 4 + j;
      int h = idx / W, w = idx - h * W;
      bool ok = valid && h > 0 && h < (H - 1) && w > 0 && w < (W - 1);
      float f = (j == 0) ? v.x : (j == 1) ? v.y : (j == 2) ? v.z : v.w;
      float vv = (f - mn) * invd * 256.0f;
      int bin = (int)(vv * 0.0234375f);             // * (6/256)
      bin = bin < 0 ? 0 : (bin > 5 ? 5 : bin);
      float tt = vv * 6.0f - 1.0f;
      int li = (int)tt;                              // trunc, matches astype(int32)
      li = li < 0 ? 0 : (li > 5 ? 5 : li);
      cbin += (unsigned long long)ok << (bin * 10);
      clut += (unsigned long long)ok << (li * 10);
    }
  }
}

__global__ __launch_bounds__(256) void k_hist(Meta m, const float* cpart, unsigned* hpart) {
  int b = blockIdx.x;
  int t = segOf(m.mmOff, b);
  int local = b - m.mmOff[t];
  int nch = m.nchMM[t];
  int c = local / nch, k = local - c * nch;
  int HW = m.H[t] * m.H[t];
  const float* ch = m.x[t] + (size_t)c * HW;
  // inline reduce of this channel's minmax partials (<=7, wave-uniform loads)
  int cb = m.mmOff[t] + c * nch;
  float mn = INFINITY, mx = -INFINITY;
  for (int kk = 0; kk < nch; kk++) {
    mn = fminf(mn, cpart[2 * (cb + kk)]);
    mx = fmaxf(mx, cpart[2 * (cb + kk) + 1]);
  }
  mn = fminf(mn, 0.f);  // fold border zeros
  mx = fmaxf(mx, 0.f);
  float d = mx - mn;
  float invd = d > 0.f ? 1.0f / d : 0.f;
  int pix0 = k * PIXB, pix1 = min(pix0 + PIXB, HW);
  unsigned long long cbin = 0ull, clut = 0ull;
  switch (m.H[t]) {
    case 224: hist_body<224>(ch, pix0, pix1, mn, invd, cbin, clut); break;
    case 112: hist_body<112>(ch, pix0, pix1, mn, invd, cbin, clut); break;
    case 56:  hist_body<56>(ch, pix0, pix1, mn, invd, cbin, clut); break;
    case 28:  hist_body<28>(ch, pix0, pix1, mn, invd, cbin, clut); break;
    default:  hist_body<14>(ch, pix0, pix1, mn, invd, cbin, clut); break;
  }
  // extract 6+6 fields, pack lo|hi 16-bit, wave-reduce (sums <= 2048 per half: no carry)
  unsigned pk[6];
#pragma unroll
  for (int j = 0; j < 6; j++)
    pk[j] = (unsigned)((cbin >> (10 * j)) & 1023ull) | ((unsigned)((clut >> (10 * j)) & 1023ull) << 16);
#pragma unroll
  for (int o = 32; o > 0; o >>= 1) {
#pragma unroll
    for (int j = 0; j < 6; j++) pk[j] += __shfl_down(pk[j], o);
  }
  __shared__ unsigned swh[4][12];
  int wid = threadIdx.x >> 6, lane = threadIdx.x & 63;
  if (lane == 0) {
#pragma unroll
    for (int j = 0; j < 6; j++) { swh[wid][j] = pk[j] & 0xffffu; swh[wid][6 + j] = pk[j] >> 16; }
  }
  __syncthreads();
  if (threadIdx.x < 12)
    hpart[12 * b + threadIdx.x] =
        swh[0][threadIdx.x] + swh[1][threadIdx.x] + swh[2][threadIdx.x] + swh[3][threadIdx.x];
}

// ---------------- K3: per-pixel p map; LUT computed in-block from partials ----------------
template <int HH>
__device__ __forceinline__ void pm_inner(const float* __restrict__ X, int i4, bool act,
                                         int c0, int c1, const float* sLut,
                                         const float* sMn, const float* sInv, float* a) {
  constexpr int W = HH, H = HH;
  constexpr int i4n = (H * W) / 4;
  if (!act) return;
  int bf[4];
#pragma unroll
  for (int j = 0; j < 4; j++) {
    int idx = i4 * 4 + j;
    int h = idx / W, w = idx - h * W;
    bf[j] = (h == 0 || h == H - 1 || w == 0 || w == W - 1) ? 1 : 0;
  }
  const float4* Xp = reinterpret_cast<const float4*>(X);
#pragma unroll 4
  for (int c = c0; c < c1; ++c) {
    float4 v = Xp[(size_t)c * i4n + i4];
    float mnc = sMn[c], ivc = sInv[c];
    const float* L = sLut + c * 8;
    float fv0 = v.x, fv1 = v.y, fv2 = v.z, fv3 = v.w;
    { float vv = (fv0 - mnc) * ivc * 256.0f; float tt = vv * 6.0f - 1.0f; int li = (int)tt; li = li < 0 ? 0 : (li > 5 ? 5 : li); a[0] += L[bf[0] ? 6 : li]; }
    { float vv = (fv1 - mnc) * ivc * 256.0f; float tt = vv * 6.0f - 1.0f; int li = (int)tt; li = li < 0 ? 0 : (li > 5 ? 5 : li); a[1] += L[bf[1] ? 6 : li]; }
    { float vv = (fv2 - mnc) * ivc * 256.0f; float tt = vv * 6.0f - 1.0f; int li = (int)tt; li = li < 0 ? 0 : (li > 5 ? 5 : li); a[2] += L[bf[2] ? 6 : li]; }
    { float vv = (fv3 - mnc) * ivc * 256.0f; float tt = vv * 6.0f - 1.0f; int li = (int)tt; li = li < 0 ? 0 : (li > 5 ? 5 : li); a[3] += L[bf[3] ? 6 : li]; }
  }
}

__global__ __launch_bounds__(512) void k_pmap(Meta m, const float* cpart, const unsigned* hpart,
                                              float* pmaps, float* ppart) {
  __shared__ float sLut[512 * 8];
  __shared__ float sMn[512], sInv[512];
  __shared__ float sAcc[8][256];
  int b = blockIdx.x;
  int t = segOf(m.pmOff, b);
  int blk = b - m.pmOff[t];
  int C = m.C[t], H = m.H[t], W = H, HW = H * W;
  int nch = m.nchMM[t];
  int tid = threadIdx.x;
  if (tid < C) {
    // --- per-channel LUT from partials (redundant per block; deterministic) ---
    int cb = m.mmOff[t] + tid * nch;
    float mn = INFINITY, mx = -INFINITY;
    unsigned hh[12];
#pragma unroll
    for (int j = 0; j < 12; j++) hh[j] = 0u;
    for (int k = 0; k < nch; k++) {
      mn = fminf(mn, cpart[2 * (cb + k)]);
      mx = fmaxf(mx, cpart[2 * (cb + k) + 1]);
#pragma unroll
      for (int j = 0; j < 12; j++) hh[j] += hpart[12 * (cb + k) + j];
    }
    mn = fminf(mn, 0.f); mx = fmaxf(mx, 0.f);
    float d = mx - mn;
    float invd = d > 0.f ? 1.0f / d : 0.f;
    float fHW = (float)HW;
    int nb = 2 * (H + W) - 4;
    // border pixel (value 0) bin/lut indices
    float vb = (0.f - mn) * invd * 256.0f;
    int bin_b = (int)(vb * 0.0234375f);
    bin_b = bin_b < 0 ? 0 : (bin_b > 5 ? 5 : bin_b);
    float ttb = vb * 6.0f - 1.0f;
    int lib = (int)ttb;
    lib = lib < 0 ? 0 : (lib > 5 ? 5 : lib);
    hh[bin_b] += (unsigned)nb;      // reconstruct full-mask histograms
    hh[6 + lib] += (unsigned)nb;
    float hl[6];
#pragma unroll
    for (int j = 0; j < 6; j++) hl[j] = -logf((float)hh[j] / fHW + 1e-4f);
    float mn2 = INFINITY, mx2 = -INFINITY, sum2 = 0.f;
#pragma unroll
    for (int j = 0; j < 6; j++) {
      unsigned cc = hh[6 + j];
      if (cc) { mn2 = fminf(mn2, hl[j]); mx2 = fmaxf(mx2, hl[j]); sum2 += (float)cc * hl[j]; }
    }
    float d2 = mx2 - mn2;
    float RL[6];
    if (d2 > 0.f) {
      float meanN = (sum2 / fHW - mn2) / d2;
      float w = 1.0f - meanN; w *= w;
#pragma unroll
      for (int j = 0; j < 6; j++) RL[j] = (hl[j] - mn2) / d2 * w;
    } else {
#pragma unroll
      for (int j = 0; j < 6; j++) RL[j] = 0.f;
    }
    float LUT[7];
    if (tid == 0) {
      float mnr = INFINITY, mxr = -INFINITY, sumr = 0.f;
#pragma unroll
      for (int j = 0; j < 6; j++) {
        unsigned cc = hh[6 + j];
        if (cc) { mnr = fminf(mnr, RL[j]); mxr = fmaxf(mxr, RL[j]); sumr += (float)cc * RL[j]; }
      }
      float dr = mxr - mnr;
      if (dr > 0.f) {
        float meanr = sumr / fHW;
        float wp = mxr - meanr; wp *= wp;
#pragma unroll
        for (int j = 0; j < 6; j++) LUT[j] = (RL[j] - mnr) / dr * wp;
        LUT[6] = LUT[lib];
      } else {
#pragma unroll
        for (int j = 0; j < 7; j++) LUT[j] = 0.f;
      }
    } else {
      float mnr = 0.f, mxr = 0.f, sumr = 0.f;
#pragma unroll
      for (int j = 0; j < 6; j++) {
        int cc = (int)hh[6 + j] - (j == lib ? nb : 0);
        if (cc > 0) { mnr = fminf(mnr, RL[j]); mxr = fmaxf(mxr, RL[j]); sumr += (float)cc * RL[j]; }
      }
      float dr = mxr - mnr;
      if (dr > 0.f) {
        float meanr = sumr / fHW;
        float wp = mxr - meanr; wp *= wp;
#pragma unroll
        for (int j = 0; j < 6; j++) LUT[j] = (RL[j] - mnr) / dr * wp;
        LUT[6] = (0.f - mnr) / dr * wp;
      } else {
#pragma unroll
        for (int j = 0; j < 7; j++) LUT[j] = 0.f;
      }
    }
#pragma unroll
    for (int j = 0; j < 7; j++) sLut[tid * 8 + j] = LUT[j];
    sLut[tid * 8 + 7] = 0.f;
    sMn[tid] = mn; sInv[tid] = invd;
  }
  __syncthreads();
  int wid = tid >> 6, lane = tid & 63;
  int i4n = HW >> 2;
  int i4 = blk * 64 + lane;
  bool act = i4 < i4n;
  float a[4] = {0.f, 0.f, 0.f, 0.f};
  int cpw = C >> 3;
  switch (H) {
    case 224: pm_inner<224>(m.x[t], i4, act, wid * cpw, (wid + 1) * cpw, sLut, sMn, sInv, a); break;
    case 112: pm_inner<112>(m.x[t], i4, act, wid * cpw, (wid + 1) * cpw, sLut, sMn, sInv, a); break;
    case 56:  pm_inner<56>(m.x[t], i4, act, wid * cpw, (wid + 1) * cpw, sLut, sMn, sInv, a); break;
    case 28:  pm_inner<28>(m.x[t], i4, act, wid * cpw, (wid + 1) * cpw, sLut, sMn, sInv, a); break;
    default:  pm_inner<14>(m.x[t], i4, act, wid * cpw, (wid + 1) * cpw, sLut, sMn, sInv, a); break;
  }
  *reinterpret_cast<float4*>(&sAcc[wid][lane * 4]) = make_float4(a[0], a[1], a[2], a[3]);
  __syncthreads();
  if (wid == 0) {
    float bmn = INFINITY, bmx = -INFINITY;
    if (act) {
      float t0 = 0.f, t1 = 0.f, t2 = 0.f, t3 = 0.f;
#pragma unroll
      for (int w = 0; w < 8; w++) {   // ascending w == ascending channel blocks (ref order)
        const float* s = &sAcc[w][lane * 4];
        t0 += s[0]; t1 += s[1]; t2 += s[2]; t3 += s[3];
      }
      size_t o = (size_t)m.pixOff[t] + (size_t)i4 * 4;
      *reinterpret_cast<float4*>(pmaps + o) = make_float4(t0, t1, t2, t3);
      bmn = fminf(fminf(t0, t1), fminf(t2, t3));
      bmx = fmaxf(fmaxf(t0, t1), fmaxf(t2, t3));
    }
#pragma unroll
    for (int o = 32; o > 0; o >>= 1) {
      bmn = fminf(bmn, __shfl_down(bmn, o));
      bmx = fmaxf(bmx, __shfl_down(bmx, o));
    }
    if (lane == 0) { ppart[2 * b] = bmn; ppart[2 * b + 1] = bmx; }
  }
}

// ---------------- K4: bilinear resize + norm; per-block (mn,mx,sum) partials ----------------
__global__ __launch_bounds__(256) void k_resize(Meta m, const float* pmaps, const float* ppart,
                                                float* mmaps, float* rpart) {
  __shared__ float sMnT, sInvT;
  int t = blockIdx.x / 225;
  int blk = blockIdx.x % 225;
  int wid = threadIdx.x >> 6, lane = threadIdx.x & 63;
  if (wid == 0) {
    int n = m.pmOff[t + 1] - m.pmOff[t];        // <= 196 partials
    const float* pp = ppart + (size_t)m.pmOff[t] * 2;
    float mn = INFINITY, mx = -INFINITY;
    for (int i = lane; i < n; i += 64) { mn = fminf(mn, pp[2 * i]); mx = fmaxf(mx, pp[2 * i + 1]); }
#pragma unroll
    for (int o = 32; o > 0; o >>= 1) {
      mn = fminf(mn, __shfl_down(mn, o));
      mx = fmaxf(mx, __shfl_down(mx, o));
    }
    if (lane == 0) {
      float d = mx - mn;
      sMnT = mn; sInvT = d > 0.f ? 1.0f / d : 0.f;
    }
  }
  __syncthreads();
  int pix = blk * 256 + threadIdx.x;  // 225*256 == 57600 exactly
  int H = m.H[t], W = m.H[t];
  const float* p = pmaps + m.pixOff[t];
  float mn = sMnT, a = sInvT;
  int oy = pix / 240, ox = pix - oy * 240;
  float hs = m.hsc[t];
  float sy = ((float)oy + 0.5f) * hs - 0.5f;
  float sx = ((float)ox + 0.5f) * hs - 0.5f;
  float fy0 = floorf(sy), fx0 = floorf(sx);
  float fy = sy - fy0, fx = sx - fx0;
  int iy0 = (int)fy0, ix0 = (int)fx0;
  int y0 = iy0 < 0 ? 0 : (iy0 > H - 1 ? H - 1 : iy0);
  int y1 = iy0 + 1 < 0 ? 0 : (iy0 + 1 > H - 1 ? H - 1 : iy0 + 1);
  int x0 = ix0 < 0 ? 0 : (ix0 > W - 1 ? W - 1 : ix0);
  int x1 = ix0 + 1 < 0 ? 0 : (ix0 + 1 > W - 1 ? W - 1 : ix0 + 1);
  float v00 = p[y0 * W + x0], v01 = p[y0 * W + x1];
  float v10 = p[y1 * W + x0], v11 = p[y1 * W + x1];
  float r = (1.f - fy) * ((1.f - fx) * v00 + fx * v01) + fy * ((1.f - fx) * v10 + fx * v11);
  float mv = (r - mn) * a;
  mmaps[(size_t)t * RHW + pix] = mv;
  float bmn = mv, bmx = mv, bsm = mv;
#pragma unroll
  for (int o = 32; o > 0; o >>= 1) {
    bmn = fminf(bmn, __shfl_down(bmn, o));
    bmx = fmaxf(bmx, __shfl_down(bmx, o));
    bsm += __shfl_down(bsm, o);
  }
  __shared__ float smn[4], smx[4], ssm[4];
  if ((threadIdx.x & 63) == 0) { smn[wid] = bmn; smx[wid] = bmx; ssm[wid] = bsm; }
  __syncthreads();
  if (threadIdx.x == 0) {
    for (int i = 1; i < 4; i++) { bmn = fminf(bmn, smn[i]); bmx = fmaxf(bmx, smx[i]); bsm += ssm[i]; }
    float* rp = rpart + ((size_t)t * 225 + blk) * 3;
    rp[0] = bmn; rp[1] = bmx; rp[2] = bsm;
  }
}

// ---------------- K5: fuse group (inline partial reduce) ----------------
__global__ __launch_bounds__(256) void k_fuse(const float* mmaps, const float* rpart,
                                              float* fusedm, float* fpart) {
  __shared__ float sMn[3], sD[3], sW[3];
  int g = blockIdx.x / 225;
  int blk = blockIdx.x % 225;
  const int gs[6] = {0, 2, 4, 7, 10, 13};
  int nt = gs[g + 1] - gs[g];
  int wid = threadIdx.x >> 6, lane = threadIdx.x & 63;
  if (wid < nt) {
    int t = gs[g] + wid;
    const float* rp = rpart + (size_t)t * 225 * 3;
    float mn = INFINITY, mx = -INFINITY, sm = 0.f;
    for (int i = lane; i < 225; i += 64) {
      mn = fminf(mn, rp[3 * i]); mx = fmaxf(mx, rp[3 * i + 1]); sm += rp[3 * i + 2];
    }
#pragma unroll
    for (int o = 32; o > 0; o >>= 1) {
      mn = fminf(mn, __shfl_down(mn, o));
      mx = fmaxf(mx, __shfl_down(mx, o));
      sm += __shfl_down(sm, o);
    }
    if (lane == 0) {
      float d = mx - mn;
      if (d > 0.f) {
        float mean = sm * (1.0f / 57600.0f);
        float w = mx - mean; w *= w;
        sMn[wid] = mn; sD[wid] = d; sW[wid] = w;
      } else {
        sMn[wid] = 0.f; sD[wid] = 0.f; sW[wid] = 0.f;
      }
    }
  }
  __syncthreads();
  int pix = blk * 256 + threadIdx.x;
  float acc = 0.f;
  for (int k = 0; k < nt; k++) {
    int t = gs[g] + k;
    if (sD[k] > 0.f) acc += (mmaps[(size_t)t * RHW + pix] - sMn[k]) / sD[k] * sW[k];
  }
  fusedm[(size_t)g * RHW + pix] = acc;
  float bmn = acc, bmx = acc;
#pragma unroll
  for (int o = 32; o > 0; o >>= 1) {
    bmn = fminf(bmn, __shfl_down(bmn, o));
    bmx = fmaxf(bmx, __shfl_down(bmx, o));
  }
  __shared__ float smn[4], smx[4];
  if ((threadIdx.x & 63) == 0) { smn[wid] = bmn; smx[wid] = bmx; }
  __syncthreads();
  if (threadIdx.x == 0) {
    for (int i = 1; i < 4; i++) { bmn = fminf(bmn, smn[i]); bmx = fmaxf(bmx, smx[i]); }
    float* fp = fpart + ((size_t)g * 225 + blk) * 2;
    fp[0] = bmn; fp[1] = bmx;
  }
}

// ---------------- K6: final outputs (inline fstats reduce) ----------------
__global__ __launch_bounds__(256) void k_out(const float* fusedm, const float* fpart, float* out) {
  __shared__ float fmn[5], finv[5];
  int wid = threadIdx.x >> 6, lane = threadIdx.x & 63;
  for (int g = wid; g < 5; g += 4) {
    const float* fp = fpart + (size_t)g * 225 * 2;
    float mn = INFINITY, mx = -INFINITY;
    for (int i = lane; i < 225; i += 64) {
      mn = fminf(mn, fp[2 * i]); mx = fmaxf(mx, fp[2 * i + 1]);
    }
#pragma unroll
    for (int o = 32; o > 0; o >>= 1) {
      mn = fminf(mn, __shfl_down(mn, o));
      mx = fmaxf(mx, __shfl_down(mx, o));
    }
    if (lane == 0) {
      float d = mx - mn;
      fmn[g] = mn; finv[g] = d > 0.f ? 256.0f / d : 0.f;
    }
  }
  __syncthreads();
  int pix = blockIdx.x * 256 + threadIdx.x;
  float acc = 0.f;
  float* out2 = out + RHW;
#pragma unroll
  for (int g = 0; g < 5; g++) {
    float v = (fusedm[(size_t)g * RHW + pix] - fmn[g]) * finv[g];
    out2[(size_t)pix * 5 + g] = v;
    acc += v;
  }
  out[pix] = acc;
}

extern "C" void kernel_launch(void* const* d_in, const int* in_sizes, int n_in,
                              void* d_out, int out_size, void* d_ws, size_t ws_size,
                              hipStream_t stream) {
  static const int Cs[NT] = {64, 64, 128, 128, 256, 256, 256, 512, 512, 512, 512, 512, 512};
  static const int Hs[NT] = {224, 224, 112, 112, 56, 56, 56, 28, 28, 28, 14, 14, 14};
  Meta m;
  int po = 0, mmb = 0, pmb = 0;
  for (int t = 0; t < NT; t++) {
    m.x[t] = (const float*)d_in[t];
    m.C[t] = Cs[t]; m.H[t] = Hs[t];
    m.hsc[t] = (float)((double)Hs[t] / 240.0);
    int HW = Hs[t] * Hs[t];
    m.pixOff[t] = po; po += HW;
    m.mmOff[t] = mmb;
    m.nchMM[t] = (HW + PIXB - 1) / PIXB;
    mmb += Cs[t] * m.nchMM[t];
    m.pmOff[t] = pmb;
    pmb += (HW + 255) / 256;
  }
  m.pixOff[NT] = po; m.mmOff[NT] = mmb; m.pmOff[NT] = pmb;

  size_t off = 0;
  auto a16 = [](size_t x) { return (x + 15) & ~(size_t)15; };
#define WALLOC(var, type, count) type* var = (type*)((char*)d_ws + off); off = a16(off + sizeof(type) * (size_t)(count));
  WALLOC(cpart, float, 2 * mmb)
  WALLOC(hpart, unsigned, 12 * mmb)
  WALLOC(ppart, float, 2 * pmb)
  WALLOC(rpart, float, NT * 225 * 3)
  WALLOC(fpart, float, 5 * 225 * 2)
  WALLOC(pmaps, float, po)
  WALLOC(mmaps, float, NT * RHW)
  WALLOC(fusedm, float, 5 * RHW)
#undef WALLOC

  hipLaunchKernelGGL(k_minmax, dim3(mmb), dim3(256), 0, stream, m, cpart);
  hipLaunchKernelGGL(k_hist, dim3(mmb), dim3(256), 0, stream, m, cpart, hpart);
  hipLaunchKernelGGL(k_pmap, dim3(pmb), dim3(512), 0, stream, m, cpart, hpart, pmaps, ppart);
  hipLaunchKernelGGL(k_resize, dim3(NT * 225), dim3(256), 0, stream, m, pmaps, ppart, mmaps, rpart);
  hipLaunchKernelGGL(k_fuse, dim3(5 * 225), dim3(256), 0, stream, mmaps, rpart, fusedm, fpart);
  hipLaunchKernelGGL(k_out, dim3(225), dim3(256), 0, stream, fusedm, fpart, (float*)d_out);
}